// Round 11
// baseline (875.155 us; speedup 1.0000x reference)
//
#include <hip/hip_runtime.h>
#include <hip/hip_bf16.h>
#include <math.h>

// Problem constants (BigBird regressor, B=2, S=4096)
#define D_    768
#define H_    12
#define DH_   64
#define BLK_  64
#define L_    2
#define R_    3
#define B_    2
#define S_    4096
#define NB_   64          // S_/BLK_
#define M_    (B_*S_)     // 8192 tokens
#define FF_   (4*D_)      // 3072
#define NCH_  8           // split-K chunks for full-attention rows
#define QK2S_ (2*D_)      // fused q|k row stride (1536)

#define PSTR  72          // P LDS row stride (u16); 72*2=144B = 9*16 -> b128-aligned rows
#define SOFT_SHIFT 8.0f   // constant softmax shift (scores ~N(0,0.3); overflow needs s>100)

typedef unsigned short u16;
typedef __bf16 bf16x8 __attribute__((ext_vector_type(8)));
typedef float  f32x4  __attribute__((ext_vector_type(4)));

// GEMM LDS chunk address (16B units): grouped layout + XOR swizzle.
// Layout: [rowgrp(0..)][ca(0..3)][row16(0..15)] with row16 ^= ca<<1.
// - fragment reads: 2-way (free); conflicts verified 0 (r5).
// r10: staging uses global_load_lds DMA — LDS dest is LINEAR
// (wave base + lane*16); the swizzle is applied to the per-lane GLOBAL
// source row instead (m173 pattern), so slot contents are bit-identical.
#define GLDS(rowgrp, ca, row16) (((rowgrp) * 64 + (ca) * 16 + ((row16) ^ ((ca) << 1))) * 8)

// async global->LDS, 16B per lane, dest = wave-uniform base + lane*16
__device__ inline void gload_lds16(const u16* g, u16* l) {
    __builtin_amdgcn_global_load_lds(
        (const __attribute__((address_space(1))) void*)g,
        (__attribute__((address_space(3))) void*)l, 16, 0, 0);
}

// ---------------------------------------------------------------- helpers

__device__ inline float gelu_f(float x) {
    // exact tanh-gelu via exp: tanh(y) = 1 - 2/(e^{2y}+1)
    float y = 0.7978845608f * (x + 0.044715f * x * x * x);
    float e = __expf(2.f * y);
    float th = 1.f - 2.f / (e + 1.f);
    return 0.5f * x * (1.f + th);
}

__device__ inline u16 f2bf(float f) {
    union { __hip_bfloat16 h; u16 u; } cv;
    cv.h = __float2bfloat16(f);
    return cv.u;
}

__device__ inline float block_reduce_sum(float v, float* red) {
#pragma unroll
    for (int o = 32; o > 0; o >>= 1) v += __shfl_xor(v, o, 64);
    int wv = threadIdx.x >> 6;
    if ((threadIdx.x & 63) == 0) red[wv] = v;
    __syncthreads();
    float tot = red[0] + red[1] + red[2] + red[3];
    __syncthreads();
    return tot;
}

// XCD-aware bijective block swizzle (requires gx*gy % 8 == 0).
__device__ inline int xcd_lid() {
    const int hid = blockIdx.y * gridDim.x + blockIdx.x;
    const int chunk = (gridDim.x * gridDim.y) >> 3;
    return (hid & 7) * chunk + (hid >> 3);
}

// ---------------------------------------------------------------- fused weight transpose-cast

__global__ __launch_bounds__(256) void tcast_all_kernel(
    const float* __restrict__ Wq, const float* __restrict__ Wk,
    const float* __restrict__ Wv, const float* __restrict__ Wo,
    const float* __restrict__ W1, const float* __restrict__ W2,
    u16* __restrict__ wqkvb, u16* __restrict__ wob,
    u16* __restrict__ w1b, u16* __restrict__ w2b)
{
    __shared__ float tile[32][33];
    int idx = blockIdx.x;
    const int l = idx / 6912; idx -= l * 6912;
    const float* in; u16* outp; int K, N, x, y;
    if (idx < 2304) {
        int m = idx / 576, tt = idx % 576;
        x = tt % 24; y = tt / 24; K = D_; N = D_;
        const size_t wo = (size_t)l * D_ * D_;
        if (m == 0)      { in = Wq + wo; outp = wqkvb + (size_t)l * 3 * D_ * D_; }
        else if (m == 1) { in = Wk + wo; outp = wqkvb + (size_t)l * 3 * D_ * D_ + (size_t)D_ * D_; }
        else if (m == 2) { in = Wv + wo; outp = wqkvb + (size_t)l * 3 * D_ * D_ + (size_t)2 * D_ * D_; }
        else             { in = Wo + wo; outp = wob + wo; }
    } else if (idx < 4608) {
        int tt = idx - 2304;
        x = tt % 96; y = tt / 96; K = D_; N = FF_;
        in = W1 + (size_t)l * D_ * FF_; outp = w1b + (size_t)l * FF_ * D_;
    } else {
        int tt = idx - 4608;
        x = tt % 24; y = tt / 24; K = FF_; N = D_;
        in = W2 + (size_t)l * FF_ * D_; outp = w2b + (size_t)l * D_ * FF_;
    }
    const int n0 = x * 32, k0 = y * 32;
    const int tx = threadIdx.x & 31, ty = threadIdx.x >> 5;
#pragma unroll
    for (int p = 0; p < 4; p++)
        tile[ty + p * 8][tx] = in[(size_t)(k0 + ty + p * 8) * N + n0 + tx];
    __syncthreads();
#pragma unroll
    for (int p = 0; p < 4; p++)
        outp[(size_t)(n0 + ty + p * 8) * K + k0 + tx] = f2bf(tile[tx][ty + p * 8]);
}

__global__ __launch_bounds__(256) void bias_cat_kernel(
    const float* __restrict__ bq, const float* __restrict__ bk,
    const float* __restrict__ bv, float* __restrict__ o)
{
    int i = blockIdx.x * 256 + threadIdx.x;        // L_*3*D_ total
    int l = i / (3 * D_), c = i % (3 * D_);
    float v = (c < D_) ? bq[(size_t)l * D_ + c]
            : (c < 2 * D_) ? bk[(size_t)l * D_ + (c - D_)]
            : bv[(size_t)l * D_ + (c - 2 * D_)];
    o[i] = v;
}

// ---------------------------------------------------------------- embed+LN

__global__ __launch_bounds__(256) void embed_ln_kernel(
    const int* __restrict__ ids, const float* __restrict__ etok,
    const float* __restrict__ epos, const float* __restrict__ g,
    const float* __restrict__ bb, float* __restrict__ x, u16* __restrict__ xb)
{
    __shared__ float red[4];
    const int tok = blockIdx.x;
    const int s   = tok & (S_ - 1);
    const int id  = ids[tok];
    const int t   = threadIdx.x;
    float v[3];
    float sum = 0.f;
#pragma unroll
    for (int i = 0; i < 3; i++) {
        int d = t + i * 256;
        v[i] = etok[(size_t)id * D_ + d] + epos[(size_t)s * D_ + d];
        sum += v[i];
    }
    float mean = block_reduce_sum(sum, red) * (1.f / 768.f);
    float sq = 0.f;
#pragma unroll
    for (int i = 0; i < 3; i++) { float dd = v[i] - mean; sq += dd * dd; }
    float var = block_reduce_sum(sq, red) * (1.f / 768.f);
    float inv = rsqrtf(var + 1e-12f);
#pragma unroll
    for (int i = 0; i < 3; i++) {
        int d = t + i * 256;
        float o = (v[i] - mean) * inv * g[d] + bb[d];
        x[(size_t)tok * D_ + d] = o;
        xb[(size_t)tok * D_ + d] = f2bf(o);
    }
}

// ---------------------------------------------------------------- add + LN (in-place on x; also writes bf16 xb)

template <int YB>
__global__ __launch_bounds__(256) void add_ln_kernel(
    float* __restrict__ x, const float* __restrict__ y,
    const float* __restrict__ yb,
    const float* __restrict__ g, const float* __restrict__ bb,
    u16* __restrict__ xb)
{
    __shared__ float red[4];
    const int tok = blockIdx.x;
    const int t   = threadIdx.x;
    float* xr = x + (size_t)tok * D_;
    const float* yr = y + (size_t)tok * D_;
    float v[3];
    float sum = 0.f;
#pragma unroll
    for (int i = 0; i < 3; i++) {
        int d = t + i * 256;
        float bv = 0.f;
        if constexpr (YB) bv = yb[d];
        v[i] = xr[d] + yr[d] + bv;
        sum += v[i];
    }
    float mean = block_reduce_sum(sum, red) * (1.f / 768.f);
    float sq = 0.f;
#pragma unroll
    for (int i = 0; i < 3; i++) { float dd = v[i] - mean; sq += dd * dd; }
    float var = block_reduce_sum(sq, red) * (1.f / 768.f);
    float inv = rsqrtf(var + 1e-12f);
#pragma unroll
    for (int i = 0; i < 3; i++) {
        int d = t + i * 256;
        float o = (v[i] - mean) * inv * g[d] + bb[d];
        xr[d] = o;
        xb[(size_t)tok * D_ + d] = f2bf(o);
    }
}

// ---------------------------------------------------------------- bf16 MFMA GEMM (128x128 tile)
// Double-buffered LDS, ONE barrier per K-step; XCD swizzle.
// r10: staging via global_load_lds (16B DMA). Per wave: 2x1KB for A + 2x1KB
// for B per K-step. LDS dest linear; source row pre-swizzled so slot
// contents match the GLDS read layout exactly (bit-identical to reg-staging).

template <int ACT, int OBF, int NN, int KK>
__global__ __launch_bounds__(256) void gemm_bf16_kernel(
    const u16* __restrict__ A, const u16* __restrict__ Wt,
    const float* __restrict__ bias, void* __restrict__ Cv)
{
    __shared__ __align__(16) u16 As[2][4096];   // 128x32 bf16 x2
    __shared__ __align__(16) u16 Bs[2][4096];
    const int t = threadIdx.x;
    const int gx = gridDim.x;
    const int lid = xcd_lid();
    const int row0 = (lid / gx) * 128, col0 = (lid % gx) * 128;
    const int w = t >> 6, lane = t & 63;
    const int wr = w >> 1, wc = w & 1;
    const int i16 = lane & 15, qd = lane >> 4;

    const f32x4 zero = {0.f, 0.f, 0.f, 0.f};
    f32x4 acc[4][4];
#pragma unroll
    for (int r = 0; r < 4; r++)
#pragma unroll
        for (int c = 0; c < 4; c++) acc[r][c] = zero;

    // DMA source decoding: thread covers LDS slots t and t+256 (linear).
    // Slot s holds global chunk (rowgrp=s>>6, ca=(s>>4)&3, row16=(s&15)^(ca<<1)).
    const int s0 = t, s1 = t + 256;
    const int ca0 = (s0 >> 4) & 3, ca1 = (s1 >> 4) & 3;
    const int gr0 = (s0 >> 6) * 16 + ((s0 & 15) ^ (ca0 << 1));
    const int gr1 = (s1 >> 6) * 16 + ((s1 & 15) ^ (ca1 << 1));
    const u16* pa0 = A  + (size_t)(row0 + gr0) * KK + ca0 * 8;
    const u16* pa1 = A  + (size_t)(row0 + gr1) * KK + ca1 * 8;
    const u16* pb0 = Wt + (size_t)(col0 + gr0) * KK + ca0 * 8;
    const u16* pb1 = Wt + (size_t)(col0 + gr1) * KK + ca1 * 8;
    const int wb0 = w * 512, wb1 = w * 512 + 2048;   // wave LDS bases (u16)

    gload_lds16(pa0, &As[0][wb0]);
    gload_lds16(pa1, &As[0][wb1]);
    gload_lds16(pb0, &Bs[0][wb0]);
    gload_lds16(pb1, &Bs[0][wb1]);
    __syncthreads();

#pragma unroll 2
    for (int k0 = 0; k0 < KK; k0 += 32) {
        const int buf = (k0 >> 5) & 1;
        const bool more = (k0 + 32 < KK);
        if (more) {                        // DMA next tile into other buffer
            int kn = k0 + 32;
            gload_lds16(pa0 + kn, &As[buf ^ 1][wb0]);
            gload_lds16(pa1 + kn, &As[buf ^ 1][wb1]);
            gload_lds16(pb0 + kn, &Bs[buf ^ 1][wb0]);
            gload_lds16(pb1 + kn, &Bs[buf ^ 1][wb1]);
        }
        bf16x8 af[4], bfr[4];
#pragma unroll
        for (int r = 0; r < 4; r++)
            af[r] = *(const bf16x8*)&As[buf][GLDS(wr * 4 + r, qd, i16)];
#pragma unroll
        for (int c = 0; c < 4; c++)
            bfr[c] = *(const bf16x8*)&Bs[buf][GLDS(wc * 4 + c, qd, i16)];
#pragma unroll
        for (int r = 0; r < 4; r++)
#pragma unroll
            for (int c = 0; c < 4; c++)
                acc[r][c] = __builtin_amdgcn_mfma_f32_16x16x32_bf16(af[r], bfr[c], acc[r][c], 0, 0, 0);
        if (more)
            __syncthreads();               // vmcnt(0) drain -> next tile ready
    }

#pragma unroll
    for (int c = 0; c < 4; c++) {
        int colg = col0 + wc * 64 + c * 16 + i16;
        float bsv = bias[colg];
#pragma unroll
        for (int r = 0; r < 4; r++) {
            int rowb = row0 + wr * 64 + r * 16 + qd * 4;
#pragma unroll
            for (int p = 0; p < 4; p++) {
                float val = acc[r][c][p] + bsv;
                if (ACT == 1) val = gelu_f(val);
                if (OBF == 1)
                    ((u16*)Cv)[(size_t)(rowb + p) * NN + colg] = f2bf(val);
                else
                    ((float*)Cv)[(size_t)(rowb + p) * NN + colg] = val;
            }
        }
    }
}

// ---------------------------------------------------------------- fused QKV GEMM (NN=2304, KK=768)
// Q,K -> fused [M,1536] bf16; V -> transposed global [B][H][DH][S] bf16
// r10: same global_load_lds staging as gemm_bf16_kernel.

__global__ __launch_bounds__(256) void gemm_qkv_kernel(
    const u16* __restrict__ A, const u16* __restrict__ Wt,
    const float* __restrict__ bias, u16* __restrict__ qk, u16* __restrict__ vtg)
{
    __shared__ __align__(16) u16 As[2][4096];
    __shared__ __align__(16) u16 Bs[2][4096];
    const int t = threadIdx.x;
    const int gx = gridDim.x;
    const int lid = xcd_lid();
    const int row0 = (lid / gx) * 128, col0 = (lid % gx) * 128;
    const int w = t >> 6, lane = t & 63;
    const int wr = w >> 1, wc = w & 1;
    const int i16 = lane & 15, qd = lane >> 4;

    const f32x4 zero = {0.f, 0.f, 0.f, 0.f};
    f32x4 acc[4][4];
#pragma unroll
    for (int r = 0; r < 4; r++)
#pragma unroll
        for (int c = 0; c < 4; c++) acc[r][c] = zero;

    const int s0 = t, s1 = t + 256;
    const int ca0 = (s0 >> 4) & 3, ca1 = (s1 >> 4) & 3;
    const int gr0 = (s0 >> 6) * 16 + ((s0 & 15) ^ (ca0 << 1));
    const int gr1 = (s1 >> 6) * 16 + ((s1 & 15) ^ (ca1 << 1));
    const u16* pa0 = A  + (size_t)(row0 + gr0) * D_ + ca0 * 8;
    const u16* pa1 = A  + (size_t)(row0 + gr1) * D_ + ca1 * 8;
    const u16* pb0 = Wt + (size_t)(col0 + gr0) * D_ + ca0 * 8;
    const u16* pb1 = Wt + (size_t)(col0 + gr1) * D_ + ca1 * 8;
    const int wb0 = w * 512, wb1 = w * 512 + 2048;

    gload_lds16(pa0, &As[0][wb0]);
    gload_lds16(pa1, &As[0][wb1]);
    gload_lds16(pb0, &Bs[0][wb0]);
    gload_lds16(pb1, &Bs[0][wb1]);
    __syncthreads();

#pragma unroll 2
    for (int k0 = 0; k0 < D_; k0 += 32) {
        const int buf = (k0 >> 5) & 1;
        const bool more = (k0 + 32 < D_);
        if (more) {
            int kn = k0 + 32;
            gload_lds16(pa0 + kn, &As[buf ^ 1][wb0]);
            gload_lds16(pa1 + kn, &As[buf ^ 1][wb1]);
            gload_lds16(pb0 + kn, &Bs[buf ^ 1][wb0]);
            gload_lds16(pb1 + kn, &Bs[buf ^ 1][wb1]);
        }
        bf16x8 af[4], bfr[4];
#pragma unroll
        for (int r = 0; r < 4; r++)
            af[r] = *(const bf16x8*)&As[buf][GLDS(wr * 4 + r, qd, i16)];
#pragma unroll
        for (int c = 0; c < 4; c++)
            bfr[c] = *(const bf16x8*)&Bs[buf][GLDS(wc * 4 + c, qd, i16)];
#pragma unroll
        for (int r = 0; r < 4; r++)
#pragma unroll
            for (int c = 0; c < 4; c++)
                acc[r][c] = __builtin_amdgcn_mfma_f32_16x16x32_bf16(af[r], bfr[c], acc[r][c], 0, 0, 0);
        if (more)
            __syncthreads();
    }

#pragma unroll
    for (int c = 0; c < 4; c++) {
        int colg = col0 + wc * 64 + c * 16 + i16;
        float bsv = bias[colg];
        if (colg < QK2S_) {                          // Q|K region
#pragma unroll
            for (int r = 0; r < 4; r++) {
                int rowb = row0 + wr * 64 + r * 16 + qd * 4;
#pragma unroll
                for (int p = 0; p < 4; p++)
                    qk[(size_t)(rowb + p) * QK2S_ + colg] = f2bf(acc[r][c][p] + bsv);
            }
        } else {                                     // V region -> transposed [B][H][DH][S]
            int cv = colg - QK2S_;
            int h = cv >> 6, d = cv & 63;
#pragma unroll
            for (int r = 0; r < 4; r++) {
                int rowb = row0 + wr * 64 + r * 16 + qd * 4;
                int bb = rowb >> 12, ss = rowb & (S_ - 1);
                uint2 o;
                o.x = (unsigned)f2bf(acc[r][c][0] + bsv) | ((unsigned)f2bf(acc[r][c][1] + bsv) << 16);
                o.y = (unsigned)f2bf(acc[r][c][2] + bsv) | ((unsigned)f2bf(acc[r][c][3] + bsv) << 16);
                *(uint2*)(vtg + (((size_t)(bb * H_ + h) * DH_ + d) * S_ + ss)) = o;
            }
        }
    }
}

// ---------------------------------------------------------------- MFMA attention core (coalesced cooperative staging)
// Each 64B line of K/V/Q fetched from global EXACTLY ONCE per block (8
// consecutive lanes cover one 128B row-segment), staged into XOR-swizzled LDS;
// all 4 waves read MFMA fragments from LDS. Double-buffered K/V, ONE barrier
// per key-block; loads issue at iteration top, ds_write after compute.
// P = exp(s/8 - SOFT_SHIFT); Ps is wave-private (in-order DS -> no barrier).
// O and l are unnormalized-but-consistent; caller divides.

__device__ inline void attn_core(
    const u16* __restrict__ qtile,   // qk + (b*S + qb*64)*1536 + h*64
    const u16* __restrict__ kbh,     // qk + 768 + b*S*1536 + h*64
    const u16* __restrict__ vth,     // vtg + (b*H + h)*64*S
    const int* kbl,                  // 8 key-block indices
    u16* Qs, u16* Ks, u16* Vs, u16* Ps,
    f32x4 (&o)[4], float (&l)[4])
{
    const int t = threadIdx.x;
    const int w = t >> 6, lane = t & 63;
    const int l15 = lane & 15, quad = lane >> 4;

    // staging mapping: thread covers 16B chunk c8w of rows r0 (li=0) / r1 (li=1)
    const int rsub = lane >> 3;            // 0..7
    const int c8w  = lane & 7;             // 0..7
    const int r0s  = w * 8 + rsub;         // rows 0..31 across waves
    const int r1s  = r0s + 32;             // rows 32..63
    const int soff0 = (r0s * 8 + (c8w ^ (r0s & 7))) * 8;   // u16 index
    const int soff1 = (r1s * 8 + (c8w ^ (r1s & 7))) * 8;

    // ---- prologue: stage Q + first K/V block (each line fetched once)
    {
        uint4 q0 = *(const uint4*)(qtile + (size_t)r0s * QK2S_ + c8w * 8);
        uint4 q1 = *(const uint4*)(qtile + (size_t)r1s * QK2S_ + c8w * 8);
        const u16* kb0 = kbh + (size_t)kbl[0] * BLK_ * QK2S_;
        const u16* vb0 = vth + kbl[0] * BLK_;
        uint4 k0 = *(const uint4*)(kb0 + (size_t)r0s * QK2S_ + c8w * 8);
        uint4 k1 = *(const uint4*)(kb0 + (size_t)r1s * QK2S_ + c8w * 8);
        uint4 v0 = *(const uint4*)(vb0 + (size_t)r0s * S_ + c8w * 8);
        uint4 v1 = *(const uint4*)(vb0 + (size_t)r1s * S_ + c8w * 8);
        *(uint4*)&Qs[soff0] = q0;  *(uint4*)&Qs[soff1] = q1;
        *(uint4*)&Ks[soff0] = k0;  *(uint4*)&Ks[soff1] = k1;
        *(uint4*)&Vs[soff0] = v0;  *(uint4*)&Vs[soff1] = v1;
    }
    __syncthreads();

    // Q fragments: row w*16+l15, chunk ki*4+quad (swizzled) -> regs, once
    const int xq = l15 & 7;
    bf16x8 qf[2];
#pragma unroll
    for (int ki = 0; ki < 2; ki++)
        qf[ki] = *(const bf16x8*)&Qs[((w * 16 + l15) * 8 + ((ki * 4 + quad) ^ xq)) * 8];

    const f32x4 zero = {0.f, 0.f, 0.f, 0.f};
#pragma unroll
    for (int c = 0; c < 4; c++) o[c] = zero;
    float ps[4] = {0.f, 0.f, 0.f, 0.f};

    const int wxor = (quad >> 1) << 4;            // P write rows quad*4+r: row bit3 = quad>>1
    const int rxor = ((l15 >> 3) & 1) << 4;       // P read row l15: row bit3 = l15>>3
    u16* pw = Ps + (w * 16 + quad * 4) * PSTR;
    const u16* pr = Ps + (w * 16 + l15) * PSTR;

    uint4 k0n, k1n, v0n, v1n;
#pragma unroll
    for (int kbi = 0; kbi < 8; kbi++) {
        // issue next block's staging loads early (hidden under this iteration)
        if (kbi + 1 < 8) {
            const u16* kbn = kbh + (size_t)kbl[kbi + 1] * BLK_ * QK2S_;
            const u16* vbn = vth + kbl[kbi + 1] * BLK_;
            k0n = *(const uint4*)(kbn + (size_t)r0s * QK2S_ + c8w * 8);
            k1n = *(const uint4*)(kbn + (size_t)r1s * QK2S_ + c8w * 8);
            v0n = *(const uint4*)(vbn + (size_t)r0s * S_ + c8w * 8);
            v1n = *(const uint4*)(vbn + (size_t)r1s * S_ + c8w * 8);
        }
        const u16* Kc = Ks + (kbi & 1) * 4096;
        const u16* Vc = Vs + (kbi & 1) * 4096;
        bf16x8 kf[4][2], vf[4][2];
#pragma unroll
        for (int c = 0; c < 4; c++)
#pragma unroll
            for (int ki = 0; ki < 2; ki++) {
                const int off = ((c * 16 + l15) * 8 + ((ki * 4 + quad) ^ xq)) * 8;
                kf[c][ki] = *(const bf16x8*)&Kc[off];
                vf[c][ki] = *(const bf16x8*)&Vc[off];
            }
        f32x4 s[4];
#pragma unroll
        for (int c = 0; c < 4; c++) s[c] = zero;
#pragma unroll
        for (int ki = 0; ki < 2; ki++)
#pragma unroll
            for (int c = 0; c < 4; c++)
                s[c] = __builtin_amdgcn_mfma_f32_16x16x32_bf16(qf[ki], kf[c][ki], s[c], 0, 0, 0);
        // constant-shift softmax numerator, in place in s
#pragma unroll
        for (int c = 0; c < 4; c++)
#pragma unroll
            for (int r = 0; r < 4; r++)
                s[c][r] = __expf(fmaf(s[c][r], 0.125f, -SOFT_SHIFT));
#pragma unroll
        for (int r = 0; r < 4; r++)
            ps[r] += (s[0][r] + s[1][r]) + (s[2][r] + s[3][r]);
        // P -> wave-private LDS (swizzled, static indexing, no barrier)
#pragma unroll
        for (int c = 0; c < 4; c++) {
            const int cbase = (c * 16 + l15) ^ wxor;
#pragma unroll
            for (int r = 0; r < 4; r++)
                pw[r * PSTR + cbase] = f2bf(s[c][r]);
        }
        // P fragments + PV (DS ops in-order per wave: reads see the writes)
#pragma unroll
        for (int ki = 0; ki < 2; ki++) {
            bf16x8 pf = *(const bf16x8*)(pr + ((ki * 32 + quad * 8) ^ rxor));
#pragma unroll
            for (int c = 0; c < 4; c++)
                o[c] = __builtin_amdgcn_mfma_f32_16x16x32_bf16(pf, vf[c][ki], o[c], 0, 0, 0);
        }
        // write next block into the other buffer; one barrier per iteration
        if (kbi + 1 < 8) {
            u16* Kn = Ks + ((kbi + 1) & 1) * 4096;
            u16* Vn = Vs + ((kbi + 1) & 1) * 4096;
            *(uint4*)&Kn[soff0] = k0n;  *(uint4*)&Kn[soff1] = k1n;
            *(uint4*)&Vn[soff0] = v0n;  *(uint4*)&Vn[soff1] = v1n;
            __syncthreads();
        }
    }
    // single final row-sum reduce across the 16 key lanes
#pragma unroll
    for (int r = 0; r < 4; r++) {
        float v = ps[r];
        v += __shfl_xor(v, 1, 16);
        v += __shfl_xor(v, 2, 16);
        v += __shfl_xor(v, 4, 16);
        v += __shfl_xor(v, 8, 16);
        l[r] = v;
    }
}

// ---------------------------------------------------------------- merged attention (sparse qblocks 1..62 + full-row chunks)

__global__ __launch_bounds__(256) void attn_kernel(
    const u16* __restrict__ qk, const u16* __restrict__ vtg,
    const int* __restrict__ rnd, u16* __restrict__ ctx,
    float* __restrict__ pctx, float* __restrict__ pl)
{
    __shared__ __align__(16) u16 Qs[4096];
    __shared__ __align__(16) u16 Ks[2 * 4096];
    __shared__ __align__(16) u16 Vs[2 * 4096];
    __shared__ __align__(16) u16 Ps[BLK_ * PSTR];

    // XCD-aware bijective swizzle: 1872 blocks = 8 XCDs x 234. Consecutive
    // logical ids (same (b,h), adjacent qblocks -> shared K/V) land on one XCD.
    const int hid = blockIdx.x + 78 * (blockIdx.y + H_ * blockIdx.z);
    const int lid = (hid & 7) * 234 + (hid >> 3);
    const int xk = lid % 78;
    const int yz = lid / 78;
    const int h = yz % H_;
    const int b = yz / H_;

    const int t = threadIdx.x;
    const int w = t >> 6, lane = t & 63;
    const int l15 = lane & 15, quad = lane >> 4;

    const bool sparse = (xk < 62);
    int qb, kbl[8], ci = 0;
    if (sparse) {
        qb = xk + 1;
        const int* rp = rnd + ((size_t)(h * NB_ + qb)) * R_;
        kbl[0] = 0; kbl[1] = qb - 1; kbl[2] = qb; kbl[3] = qb + 1;
        kbl[4] = NB_ - 1; kbl[5] = rp[0]; kbl[6] = rp[1]; kbl[7] = rp[2];
    } else {
        int e = xk - 62;
        int chunk = e & 7, qsel = e >> 3;
        qb = qsel ? (NB_ - 1) : 0;
#pragma unroll
        for (int i = 0; i < 8; i++) kbl[i] = chunk * 8 + i;
        ci = (((qsel * B_ + b) * H_ + h) * NCH_) + chunk;
    }

    const u16* qtile = qk + ((size_t)(b * S_ + qb * BLK_)) * QK2S_ + h * DH_;
    const u16* kbh   = qk + D_ + ((size_t)b * S_) * QK2S_ + h * DH_;
    const u16* vth   = vtg + ((size_t)(b * H_ + h) * DH_) * S_;

    f32x4 o[4]; float l[4];
    attn_core(qtile, kbh, vth, kbl, Qs, Ks, Vs, Ps, o, l);

    if (sparse) {
#pragma unroll
        for (int r = 0; r < 4; r++) {
            int row = w * 16 + quad * 4 + r;
            float inv = 1.f / l[r];
#pragma unroll
            for (int c = 0; c < 4; c++)
                ctx[((size_t)(b * S_ + qb * BLK_ + row)) * D_ + h * DH_ + c * 16 + l15] =
                    f2bf(o[c][r] * inv);
        }
    } else {
#pragma unroll
        for (int r = 0; r < 4; r++) {
            int row = w * 16 + quad * 4 + r;
#pragma unroll
            for (int c = 0; c < 4; c++)
                pctx[((size_t)ci * BLK_ + row) * DH_ + c * 16 + l15] = o[c][r];
            if (l15 == 0)
                pl[(size_t)ci * BLK_ + row] = l[r];
        }
    }
}

// combine: with constant shift, partials add directly (no max re-alignment)
__global__ __launch_bounds__(256) void attn_combine_kernel(
    const float* __restrict__ pctx, const float* __restrict__ pl,
    u16* __restrict__ ctx)
{
    const int qsel = blockIdx.x, h = blockIdx.y, b = blockIdx.z;
    const int qb = qsel ? (NB_ - 1) : 0;
    const int t = threadIdx.x;
    const int row = t >> 2, q4 = t & 3;
    const int cbase = ((qsel * B_ + b) * H_ + h) * NCH_;

    float L = 0.f;
#pragma unroll
    for (int c = 0; c < NCH_; c++) L += pl[(size_t)(cbase + c) * BLK_ + row];

    float acc[16];
#pragma unroll
    for (int j = 0; j < 16; j++) acc[j] = 0.f;
#pragma unroll
    for (int c = 0; c < NCH_; c++) {
        const float* src = pctx + ((size_t)(cbase + c) * BLK_ + row) * DH_ + q4 * 16;
#pragma unroll
        for (int jj = 0; jj < 4; jj++) {
            float4 f = *(const float4*)(src + jj * 4);
            acc[jj * 4 + 0] += f.x;
            acc[jj * 4 + 1] += f.y;
            acc[jj * 4 + 2] += f.z;
            acc[jj * 4 + 3] += f.w;
        }
    }
    float invL = 1.f / L;
    u16* dst = ctx + ((size_t)(b * S_ + qb * BLK_ + row)) * D_ + h * DH_ + q4 * 16;
    uint4 o0, o1;
#pragma unroll
    for (int g = 0; g < 8; g++) {
        unsigned lo = (unsigned)f2bf(acc[g * 2 + 0] * invL);
        unsigned hi = (unsigned)f2bf(acc[g * 2 + 1] * invL);
        unsigned pk = lo | (hi << 16);
        if (g < 4) (&o0.x)[g] = pk; else (&o1.x)[g - 4] = pk;
    }
    *(uint4*)dst = o0;
    *(uint4*)(dst + 8) = o1;
}

// ---------------------------------------------------------------- pooling + final dot

__global__ __launch_bounds__(256) void pool_kernel(
    const float* __restrict__ x, const float* __restrict__ fcw,
    float* __restrict__ acc)
{
    __shared__ float red[4];
    const int chunk = blockIdx.x, b = blockIdx.y;
    const int t = threadIdx.x;
    float s = 0.f;
    for (int sr = 0; sr < 128; sr++) {
        const float* xr = x + ((size_t)(b * S_ + chunk * 128 + sr)) * D_;
#pragma unroll
        for (int i = 0; i < 3; i++) {
            int d = t + i * 256;
            s += xr[d] * fcw[d];
        }
    }
    float tot = block_reduce_sum(s, red);
    if (t == 0) atomicAdd(&acc[b], tot);
}

__global__ void final_kernel(const float* __restrict__ acc,
                             const float* __restrict__ fcb,
                             float* __restrict__ out)
{
    if (threadIdx.x < B_) out[threadIdx.x] = acc[threadIdx.x] * (1.f / S_) + fcb[0];
}

// ---------------------------------------------------------------- launch

extern "C" void kernel_launch(void* const* d_in, const int* in_sizes, int n_in,
                              void* d_out, int out_size, void* d_ws, size_t ws_size,
                              hipStream_t stream)
{
    (void)in_sizes; (void)n_in; (void)out_size; (void)ws_size;
    const int*   ids  = (const int*)d_in[0];
    const int*   rnd  = (const int*)d_in[1];
    const float* etok = (const float*)d_in[2];
    const float* epos = (const float*)d_in[3];
    const float* lng  = (const float*)d_in[4];
    const float* lnb  = (const float*)d_in[5];
    const float* Wq   = (const float*)d_in[6];
    const float* bq   = (const float*)d_in[7];
    const float* Wk   = (const float*)d_in[8];
    const float* bk   = (const float*)d_in[9];
    const float* Wv   = (const float*)d_in[10];
    const float* bv   = (const float*)d_in[11];
    const float* Wo   = (const float*)d_in[12];
    const float* bo   = (const float*)d_in[13];
    const float* ln1g = (const float*)d_in[14];
    const float* ln1b = (const float*)d_in[15];
    const float* W1   = (const float*)d_in[16];
    const float* b1   = (const float*)d_in[17];
    const float* W2   = (const float*)d_in[18];
    const float* b2   = (const float*)d_in[19];
    const float* ln2g = (const float*)d_in[20];
    const float* ln2b = (const float*)d_in[21];
    const float* fcw  = (const float*)d_in[22];
    const float* fcb  = (const float*)d_in[23];
    float* out = (float*)d_out;

    // ---- workspace layout (~148 MB) ----
    const size_t MD = (size_t)M_ * D_;
    const size_t PCTX = (size_t)2 * B_ * H_ * NCH_ * BLK_ * DH_;
    const size_t PML  = (size_t)2 * B_ * H_ * NCH_ * BLK_;

    float* x     = (float*)d_ws;              // MD f32
    float* regB  = x + MD;                    // MD f32
    float* pctx  = regB + MD;                 // PCTX f32
    float* pl    = pctx + PCTX;               // PML f32
    u16*   qkb   = (u16*)(pl + PML);          // 2*MD bf16 (fused q|k per row)
    u16*   vtg   = qkb + 2 * MD;              // MD bf16, [B][H][DH][S]
    u16*   ctxb  = vtg + MD;                  // MD bf16
    u16*   ffhb  = qkb;                       // [M,FF] bf16, aliases qkb+vtg+ctxb
    u16*   xb    = ctxb + MD;                 // MD bf16
    u16*   wqkvb = xb + MD;                   // L*2304*768 bf16
    u16*   wob   = wqkvb + (size_t)L_ * 3 * D_ * D_;
    u16*   w1b   = wob + (size_t)L_ * D_ * D_;       // [L][FF][D]
    u16*   w2b   = w1b + (size_t)L_ * FF_ * D_;      // [L][D][FF]
    float* bqkv  = (float*)(w2b + (size_t)L_ * D_ * FF_);  // L*2304 f32
    float* acc   = bqkv + (size_t)L_ * 3 * D_;

    hipMemsetAsync(acc, 0, 2 * sizeof(float), stream);

    tcast_all_kernel<<<L_ * 6912, 256, 0, stream>>>(
        Wq, Wk, Wv, Wo, W1, W2, wqkvb, wob, w1b, w2b);
    bias_cat_kernel<<<(L_ * 3 * D_) / 256, 256, 0, stream>>>(bq, bk, bv, bqkv);
    embed_ln_kernel<<<M_, 256, 0, stream>>>(ids, etok, epos, lng, lnb, x, xb);

    dim3 gQKV(3 * D_ / 128, M_ / 128);     // (18, 64) = 1152 blocks (%8==0)
    dim3 g6(D_ / 128, M_ / 128);           // (6, 64)  = 384 blocks  (%8==0)
    dim3 gF(FF_ / 128, M_ / 128);          // (24, 64) = 1536 blocks (%8==0)
    for (int l = 0; l < L_; l++) {
        const size_t wo = (size_t)l * D_ * D_;
        const size_t vo = (size_t)l * D_;
        gemm_qkv_kernel<<<gQKV, 256, 0, stream>>>(
            xb, wqkvb + (size_t)l * 3 * D_ * D_, bqkv + (size_t)l * 3 * D_, qkb, vtg);
        attn_kernel<<<dim3(78, H_, B_), 256, 0, stream>>>(qkb, vtg, rnd, ctxb, pctx, pl);
        attn_combine_kernel<<<dim3(2, H_, B_), 256, 0, stream>>>(pctx, pl, ctxb);
        gemm_bf16_kernel<0, 0, D_, D_><<<g6, 256, 0, stream>>>(
            ctxb, wob + wo, bo + vo, regB);
        add_ln_kernel<0><<<M_, 256, 0, stream>>>(x, regB, nullptr, ln1g + vo, ln1b + vo, xb);
        gemm_bf16_kernel<1, 1, FF_, D_><<<gF, 256, 0, stream>>>(
            xb, w1b + (size_t)l * FF_ * D_, b1 + (size_t)l * FF_, ffhb);
        gemm_bf16_kernel<0, 0, D_, FF_><<<g6, 256, 0, stream>>>(
            ffhb, w2b + (size_t)l * D_ * FF_, b2 + vo, regB);
        add_ln_kernel<0><<<M_, 256, 0, stream>>>(x, regB, nullptr, ln2g + vo, ln2b + vo, xb);
    }
    pool_kernel<<<dim3(S_ / 128, B_), 256, 0, stream>>>(x, fcw, acc);
    final_kernel<<<1, 64, 0, stream>>>(acc, fcb, out);
}

// Round 12
// 729.321 us; speedup vs baseline: 1.2000x; 1.2000x over previous
//
#include <hip/hip_runtime.h>
#include <hip/hip_bf16.h>
#include <math.h>

// Problem constants (BigBird regressor, B=2, S=4096)
#define D_    768
#define H_    12
#define DH_   64
#define BLK_  64
#define L_    2
#define R_    3
#define B_    2
#define S_    4096
#define NB_   64          // S_/BLK_
#define M_    (B_*S_)     // 8192 tokens
#define FF_   (4*D_)      // 3072
#define NCH_  8           // split-K chunks for full-attention rows
#define QK2S_ (2*D_)      // fused q|k row stride (1536)

#define PSTR  72          // P LDS row stride (u16); 72*2=144B = 9*16 -> b128-aligned rows
#define SOFT_SHIFT 8.0f   // constant softmax shift (scores ~N(0,0.3); overflow needs s>100)

typedef unsigned short u16;
typedef __bf16 bf16x8 __attribute__((ext_vector_type(8)));
typedef float  f32x4  __attribute__((ext_vector_type(4)));

// GEMM LDS chunk address (16B units), r11 layout: [rowgrp][row16][kc] with
// kc_lds = kc ^ ((row16>>1)&3).
// - DMA staging (linear slot order == lane order): lane covers
//   (row=lane>>2, kc=(lane&3)^((row>>1)&3)) -> 4 lanes = one permuted 64B row
//   segment -> FULLY COALESCED (r10's [rowgrp][ca][row16] order put 16
//   consecutive lanes on 16 different rows -> 64 lines/instr, FETCH +45%).
// - fragment reads (i16 fast, qd fixed): chunk%8 takes all 8 values twice
//   per 16-lane quadrant -> 2-way (free).
#define GLDS(rowgrp, kc, row16) (((rowgrp) * 64 + (row16) * 4 + ((kc) ^ (((row16) >> 1) & 3))) * 8)

// async global->LDS, 16B per lane, dest = wave-uniform base + lane*16
__device__ inline void gload_lds16(const u16* g, u16* l) {
    __builtin_amdgcn_global_load_lds(
        (const __attribute__((address_space(1))) void*)g,
        (__attribute__((address_space(3))) void*)l, 16, 0, 0);
}

// ---------------------------------------------------------------- helpers

__device__ inline float gelu_f(float x) {
    // exact tanh-gelu via exp: tanh(y) = 1 - 2/(e^{2y}+1)
    float y = 0.7978845608f * (x + 0.044715f * x * x * x);
    float e = __expf(2.f * y);
    float th = 1.f - 2.f / (e + 1.f);
    return 0.5f * x * (1.f + th);
}

__device__ inline u16 f2bf(float f) {
    union { __hip_bfloat16 h; u16 u; } cv;
    cv.h = __float2bfloat16(f);
    return cv.u;
}

__device__ inline float block_reduce_sum(float v, float* red) {
#pragma unroll
    for (int o = 32; o > 0; o >>= 1) v += __shfl_xor(v, o, 64);
    int wv = threadIdx.x >> 6;
    if ((threadIdx.x & 63) == 0) red[wv] = v;
    __syncthreads();
    float tot = red[0] + red[1] + red[2] + red[3];
    __syncthreads();
    return tot;
}

// XCD-aware bijective block swizzle (requires gx*gy % 8 == 0).
__device__ inline int xcd_lid() {
    const int hid = blockIdx.y * gridDim.x + blockIdx.x;
    const int chunk = (gridDim.x * gridDim.y) >> 3;
    return (hid & 7) * chunk + (hid >> 3);
}

// ---------------------------------------------------------------- fused weight transpose-cast

__global__ __launch_bounds__(256) void tcast_all_kernel(
    const float* __restrict__ Wq, const float* __restrict__ Wk,
    const float* __restrict__ Wv, const float* __restrict__ Wo,
    const float* __restrict__ W1, const float* __restrict__ W2,
    u16* __restrict__ wqkvb, u16* __restrict__ wob,
    u16* __restrict__ w1b, u16* __restrict__ w2b)
{
    __shared__ float tile[32][33];
    int idx = blockIdx.x;
    const int l = idx / 6912; idx -= l * 6912;
    const float* in; u16* outp; int K, N, x, y;
    if (idx < 2304) {
        int m = idx / 576, tt = idx % 576;
        x = tt % 24; y = tt / 24; K = D_; N = D_;
        const size_t wo = (size_t)l * D_ * D_;
        if (m == 0)      { in = Wq + wo; outp = wqkvb + (size_t)l * 3 * D_ * D_; }
        else if (m == 1) { in = Wk + wo; outp = wqkvb + (size_t)l * 3 * D_ * D_ + (size_t)D_ * D_; }
        else if (m == 2) { in = Wv + wo; outp = wqkvb + (size_t)l * 3 * D_ * D_ + (size_t)2 * D_ * D_; }
        else             { in = Wo + wo; outp = wob + wo; }
    } else if (idx < 4608) {
        int tt = idx - 2304;
        x = tt % 96; y = tt / 96; K = D_; N = FF_;
        in = W1 + (size_t)l * D_ * FF_; outp = w1b + (size_t)l * FF_ * D_;
    } else {
        int tt = idx - 4608;
        x = tt % 24; y = tt / 24; K = FF_; N = D_;
        in = W2 + (size_t)l * FF_ * D_; outp = w2b + (size_t)l * D_ * FF_;
    }
    const int n0 = x * 32, k0 = y * 32;
    const int tx = threadIdx.x & 31, ty = threadIdx.x >> 5;
#pragma unroll
    for (int p = 0; p < 4; p++)
        tile[ty + p * 8][tx] = in[(size_t)(k0 + ty + p * 8) * N + n0 + tx];
    __syncthreads();
#pragma unroll
    for (int p = 0; p < 4; p++)
        outp[(size_t)(n0 + ty + p * 8) * K + k0 + tx] = f2bf(tile[tx][ty + p * 8]);
}

__global__ __launch_bounds__(256) void bias_cat_kernel(
    const float* __restrict__ bq, const float* __restrict__ bk,
    const float* __restrict__ bv, float* __restrict__ o)
{
    int i = blockIdx.x * 256 + threadIdx.x;        // L_*3*D_ total
    int l = i / (3 * D_), c = i % (3 * D_);
    float v = (c < D_) ? bq[(size_t)l * D_ + c]
            : (c < 2 * D_) ? bk[(size_t)l * D_ + (c - D_)]
            : bv[(size_t)l * D_ + (c - 2 * D_)];
    o[i] = v;
}

// ---------------------------------------------------------------- embed+LN

__global__ __launch_bounds__(256) void embed_ln_kernel(
    const int* __restrict__ ids, const float* __restrict__ etok,
    const float* __restrict__ epos, const float* __restrict__ g,
    const float* __restrict__ bb, float* __restrict__ x, u16* __restrict__ xb)
{
    __shared__ float red[4];
    const int tok = blockIdx.x;
    const int s   = tok & (S_ - 1);
    const int id  = ids[tok];
    const int t   = threadIdx.x;
    float v[3];
    float sum = 0.f;
#pragma unroll
    for (int i = 0; i < 3; i++) {
        int d = t + i * 256;
        v[i] = etok[(size_t)id * D_ + d] + epos[(size_t)s * D_ + d];
        sum += v[i];
    }
    float mean = block_reduce_sum(sum, red) * (1.f / 768.f);
    float sq = 0.f;
#pragma unroll
    for (int i = 0; i < 3; i++) { float dd = v[i] - mean; sq += dd * dd; }
    float var = block_reduce_sum(sq, red) * (1.f / 768.f);
    float inv = rsqrtf(var + 1e-12f);
#pragma unroll
    for (int i = 0; i < 3; i++) {
        int d = t + i * 256;
        float o = (v[i] - mean) * inv * g[d] + bb[d];
        x[(size_t)tok * D_ + d] = o;
        xb[(size_t)tok * D_ + d] = f2bf(o);
    }
}

// ---------------------------------------------------------------- add + LN (in-place on x; also writes bf16 xb)

template <int YB>
__global__ __launch_bounds__(256) void add_ln_kernel(
    float* __restrict__ x, const float* __restrict__ y,
    const float* __restrict__ yb,
    const float* __restrict__ g, const float* __restrict__ bb,
    u16* __restrict__ xb)
{
    __shared__ float red[4];
    const int tok = blockIdx.x;
    const int t   = threadIdx.x;
    float* xr = x + (size_t)tok * D_;
    const float* yr = y + (size_t)tok * D_;
    float v[3];
    float sum = 0.f;
#pragma unroll
    for (int i = 0; i < 3; i++) {
        int d = t + i * 256;
        float bv = 0.f;
        if constexpr (YB) bv = yb[d];
        v[i] = xr[d] + yr[d] + bv;
        sum += v[i];
    }
    float mean = block_reduce_sum(sum, red) * (1.f / 768.f);
    float sq = 0.f;
#pragma unroll
    for (int i = 0; i < 3; i++) { float dd = v[i] - mean; sq += dd * dd; }
    float var = block_reduce_sum(sq, red) * (1.f / 768.f);
    float inv = rsqrtf(var + 1e-12f);
#pragma unroll
    for (int i = 0; i < 3; i++) {
        int d = t + i * 256;
        float o = (v[i] - mean) * inv * g[d] + bb[d];
        xr[d] = o;
        xb[(size_t)tok * D_ + d] = f2bf(o);
    }
}

// ---------------------------------------------------------------- bf16 MFMA GEMM (128x128 tile)
// Double-buffered LDS, ONE barrier per K-step; XCD swizzle.
// r11: global_load_lds staging with COALESCED sources — slot order == lane
// order == (row=lane>>2, kc=(lane&3)^((row>>1)&3)): 4 lanes per 64B line,
// same line pattern as r9's reg-staging (r10's slot order was row-fastest ->
// 16 lanes on 16 rows -> 4x line-requests, FETCH 43.8->63.2 MB, regression).

template <int ACT, int OBF, int NN, int KK>
__global__ __launch_bounds__(256) void gemm_bf16_kernel(
    const u16* __restrict__ A, const u16* __restrict__ Wt,
    const float* __restrict__ bias, void* __restrict__ Cv)
{
    __shared__ __align__(16) u16 As[2][4096];   // 128x32 bf16 x2
    __shared__ __align__(16) u16 Bs[2][4096];
    const int t = threadIdx.x;
    const int gx = gridDim.x;
    const int lid = xcd_lid();
    const int row0 = (lid / gx) * 128, col0 = (lid % gx) * 128;
    const int w = t >> 6, lane = t & 63;
    const int wr = w >> 1, wc = w & 1;
    const int i16 = lane & 15, qd = lane >> 4;

    const f32x4 zero = {0.f, 0.f, 0.f, 0.f};
    f32x4 acc[4][4];
#pragma unroll
    for (int r = 0; r < 4; r++)
#pragma unroll
        for (int c = 0; c < 4; c++) acc[r][c] = zero;

    // DMA source decoding: thread covers LDS slots t and t+256 (linear).
    // Slot s: rowgrp=s>>6, row16=(s>>2)&15, kc_lds=s&3; holds global chunk
    // (row=rowgrp*16+row16, kc=kc_lds^((row16>>1)&3)).
    const int s0 = t, s1 = t + 256;
    const int rw0 = (s0 >> 2) & 15, rw1 = (s1 >> 2) & 15;
    const int kc0 = (s0 & 3) ^ ((rw0 >> 1) & 3);
    const int kc1 = (s1 & 3) ^ ((rw1 >> 1) & 3);
    const int gr0 = (s0 >> 6) * 16 + rw0;
    const int gr1 = (s1 >> 6) * 16 + rw1;
    const u16* pa0 = A  + (size_t)(row0 + gr0) * KK + kc0 * 8;
    const u16* pa1 = A  + (size_t)(row0 + gr1) * KK + kc1 * 8;
    const u16* pb0 = Wt + (size_t)(col0 + gr0) * KK + kc0 * 8;
    const u16* pb1 = Wt + (size_t)(col0 + gr1) * KK + kc1 * 8;
    const int wb0 = w * 512, wb1 = w * 512 + 2048;   // wave LDS bases (u16)

    gload_lds16(pa0, &As[0][wb0]);
    gload_lds16(pa1, &As[0][wb1]);
    gload_lds16(pb0, &Bs[0][wb0]);
    gload_lds16(pb1, &Bs[0][wb1]);
    __syncthreads();

#pragma unroll 2
    for (int k0 = 0; k0 < KK; k0 += 32) {
        const int buf = (k0 >> 5) & 1;
        const bool more = (k0 + 32 < KK);
        if (more) {                        // DMA next tile into other buffer
            int kn = k0 + 32;
            gload_lds16(pa0 + kn, &As[buf ^ 1][wb0]);
            gload_lds16(pa1 + kn, &As[buf ^ 1][wb1]);
            gload_lds16(pb0 + kn, &Bs[buf ^ 1][wb0]);
            gload_lds16(pb1 + kn, &Bs[buf ^ 1][wb1]);
        }
        bf16x8 af[4], bfr[4];
#pragma unroll
        for (int r = 0; r < 4; r++)
            af[r] = *(const bf16x8*)&As[buf][GLDS(wr * 4 + r, qd, i16)];
#pragma unroll
        for (int c = 0; c < 4; c++)
            bfr[c] = *(const bf16x8*)&Bs[buf][GLDS(wc * 4 + c, qd, i16)];
#pragma unroll
        for (int r = 0; r < 4; r++)
#pragma unroll
            for (int c = 0; c < 4; c++)
                acc[r][c] = __builtin_amdgcn_mfma_f32_16x16x32_bf16(af[r], bfr[c], acc[r][c], 0, 0, 0);
        if (more)
            __syncthreads();               // vmcnt(0) drain -> next tile ready
    }

#pragma unroll
    for (int c = 0; c < 4; c++) {
        int colg = col0 + wc * 64 + c * 16 + i16;
        float bsv = bias[colg];
#pragma unroll
        for (int r = 0; r < 4; r++) {
            int rowb = row0 + wr * 64 + r * 16 + qd * 4;
#pragma unroll
            for (int p = 0; p < 4; p++) {
                float val = acc[r][c][p] + bsv;
                if (ACT == 1) val = gelu_f(val);
                if (OBF == 1)
                    ((u16*)Cv)[(size_t)(rowb + p) * NN + colg] = f2bf(val);
                else
                    ((float*)Cv)[(size_t)(rowb + p) * NN + colg] = val;
            }
        }
    }
}

// ---------------------------------------------------------------- fused QKV GEMM (NN=2304, KK=768)
// Q,K -> fused [M,1536] bf16; V -> transposed global [B][H][DH][S] bf16
// r11: same coalesced global_load_lds staging as gemm_bf16_kernel.

__global__ __launch_bounds__(256) void gemm_qkv_kernel(
    const u16* __restrict__ A, const u16* __restrict__ Wt,
    const float* __restrict__ bias, u16* __restrict__ qk, u16* __restrict__ vtg)
{
    __shared__ __align__(16) u16 As[2][4096];
    __shared__ __align__(16) u16 Bs[2][4096];
    const int t = threadIdx.x;
    const int gx = gridDim.x;
    const int lid = xcd_lid();
    const int row0 = (lid / gx) * 128, col0 = (lid % gx) * 128;
    const int w = t >> 6, lane = t & 63;
    const int wr = w >> 1, wc = w & 1;
    const int i16 = lane & 15, qd = lane >> 4;

    const f32x4 zero = {0.f, 0.f, 0.f, 0.f};
    f32x4 acc[4][4];
#pragma unroll
    for (int r = 0; r < 4; r++)
#pragma unroll
        for (int c = 0; c < 4; c++) acc[r][c] = zero;

    const int s0 = t, s1 = t + 256;
    const int rw0 = (s0 >> 2) & 15, rw1 = (s1 >> 2) & 15;
    const int kc0 = (s0 & 3) ^ ((rw0 >> 1) & 3);
    const int kc1 = (s1 & 3) ^ ((rw1 >> 1) & 3);
    const int gr0 = (s0 >> 6) * 16 + rw0;
    const int gr1 = (s1 >> 6) * 16 + rw1;
    const u16* pa0 = A  + (size_t)(row0 + gr0) * D_ + kc0 * 8;
    const u16* pa1 = A  + (size_t)(row0 + gr1) * D_ + kc1 * 8;
    const u16* pb0 = Wt + (size_t)(col0 + gr0) * D_ + kc0 * 8;
    const u16* pb1 = Wt + (size_t)(col0 + gr1) * D_ + kc1 * 8;
    const int wb0 = w * 512, wb1 = w * 512 + 2048;

    gload_lds16(pa0, &As[0][wb0]);
    gload_lds16(pa1, &As[0][wb1]);
    gload_lds16(pb0, &Bs[0][wb0]);
    gload_lds16(pb1, &Bs[0][wb1]);
    __syncthreads();

#pragma unroll 2
    for (int k0 = 0; k0 < D_; k0 += 32) {
        const int buf = (k0 >> 5) & 1;
        const bool more = (k0 + 32 < D_);
        if (more) {
            int kn = k0 + 32;
            gload_lds16(pa0 + kn, &As[buf ^ 1][wb0]);
            gload_lds16(pa1 + kn, &As[buf ^ 1][wb1]);
            gload_lds16(pb0 + kn, &Bs[buf ^ 1][wb0]);
            gload_lds16(pb1 + kn, &Bs[buf ^ 1][wb1]);
        }
        bf16x8 af[4], bfr[4];
#pragma unroll
        for (int r = 0; r < 4; r++)
            af[r] = *(const bf16x8*)&As[buf][GLDS(wr * 4 + r, qd, i16)];
#pragma unroll
        for (int c = 0; c < 4; c++)
            bfr[c] = *(const bf16x8*)&Bs[buf][GLDS(wc * 4 + c, qd, i16)];
#pragma unroll
        for (int r = 0; r < 4; r++)
#pragma unroll
            for (int c = 0; c < 4; c++)
                acc[r][c] = __builtin_amdgcn_mfma_f32_16x16x32_bf16(af[r], bfr[c], acc[r][c], 0, 0, 0);
        if (more)
            __syncthreads();
    }

#pragma unroll
    for (int c = 0; c < 4; c++) {
        int colg = col0 + wc * 64 + c * 16 + i16;
        float bsv = bias[colg];
        if (colg < QK2S_) {                          // Q|K region
#pragma unroll
            for (int r = 0; r < 4; r++) {
                int rowb = row0 + wr * 64 + r * 16 + qd * 4;
#pragma unroll
                for (int p = 0; p < 4; p++)
                    qk[(size_t)(rowb + p) * QK2S_ + colg] = f2bf(acc[r][c][p] + bsv);
            }
        } else {                                     // V region -> transposed [B][H][DH][S]
            int cv = colg - QK2S_;
            int h = cv >> 6, d = cv & 63;
#pragma unroll
            for (int r = 0; r < 4; r++) {
                int rowb = row0 + wr * 64 + r * 16 + qd * 4;
                int bb = rowb >> 12, ss = rowb & (S_ - 1);
                uint2 o;
                o.x = (unsigned)f2bf(acc[r][c][0] + bsv) | ((unsigned)f2bf(acc[r][c][1] + bsv) << 16);
                o.y = (unsigned)f2bf(acc[r][c][2] + bsv) | ((unsigned)f2bf(acc[r][c][3] + bsv) << 16);
                *(uint2*)(vtg + (((size_t)(bb * H_ + h) * DH_ + d) * S_ + ss)) = o;
            }
        }
    }
}

// ---------------------------------------------------------------- MFMA attention core (coalesced cooperative staging)
// Each 64B line of K/V/Q fetched from global EXACTLY ONCE per block (8
// consecutive lanes cover one 128B row-segment), staged into XOR-swizzled LDS;
// all 4 waves read MFMA fragments from LDS. Double-buffered K/V, ONE barrier
// per key-block; loads issue at iteration top, ds_write after compute.
// P = exp(s/8 - SOFT_SHIFT); Ps is wave-private (in-order DS -> no barrier).
// O and l are unnormalized-but-consistent; caller divides.

__device__ inline void attn_core(
    const u16* __restrict__ qtile,   // qk + (b*S + qb*64)*1536 + h*64
    const u16* __restrict__ kbh,     // qk + 768 + b*S*1536 + h*64
    const u16* __restrict__ vth,     // vtg + (b*H + h)*64*S
    const int* kbl,                  // 8 key-block indices
    u16* Qs, u16* Ks, u16* Vs, u16* Ps,
    f32x4 (&o)[4], float (&l)[4])
{
    const int t = threadIdx.x;
    const int w = t >> 6, lane = t & 63;
    const int l15 = lane & 15, quad = lane >> 4;

    // staging mapping: thread covers 16B chunk c8w of rows r0 (li=0) / r1 (li=1)
    const int rsub = lane >> 3;            // 0..7
    const int c8w  = lane & 7;             // 0..7
    const int r0s  = w * 8 + rsub;         // rows 0..31 across waves
    const int r1s  = r0s + 32;             // rows 32..63
    const int soff0 = (r0s * 8 + (c8w ^ (r0s & 7))) * 8;   // u16 index
    const int soff1 = (r1s * 8 + (c8w ^ (r1s & 7))) * 8;

    // ---- prologue: stage Q + first K/V block (each line fetched once)
    {
        uint4 q0 = *(const uint4*)(qtile + (size_t)r0s * QK2S_ + c8w * 8);
        uint4 q1 = *(const uint4*)(qtile + (size_t)r1s * QK2S_ + c8w * 8);
        const u16* kb0 = kbh + (size_t)kbl[0] * BLK_ * QK2S_;
        const u16* vb0 = vth + kbl[0] * BLK_;
        uint4 k0 = *(const uint4*)(kb0 + (size_t)r0s * QK2S_ + c8w * 8);
        uint4 k1 = *(const uint4*)(kb0 + (size_t)r1s * QK2S_ + c8w * 8);
        uint4 v0 = *(const uint4*)(vb0 + (size_t)r0s * S_ + c8w * 8);
        uint4 v1 = *(const uint4*)(vb0 + (size_t)r1s * S_ + c8w * 8);
        *(uint4*)&Qs[soff0] = q0;  *(uint4*)&Qs[soff1] = q1;
        *(uint4*)&Ks[soff0] = k0;  *(uint4*)&Ks[soff1] = k1;
        *(uint4*)&Vs[soff0] = v0;  *(uint4*)&Vs[soff1] = v1;
    }
    __syncthreads();

    // Q fragments: row w*16+l15, chunk ki*4+quad (swizzled) -> regs, once
    const int xq = l15 & 7;
    bf16x8 qf[2];
#pragma unroll
    for (int ki = 0; ki < 2; ki++)
        qf[ki] = *(const bf16x8*)&Qs[((w * 16 + l15) * 8 + ((ki * 4 + quad) ^ xq)) * 8];

    const f32x4 zero = {0.f, 0.f, 0.f, 0.f};
#pragma unroll
    for (int c = 0; c < 4; c++) o[c] = zero;
    float ps[4] = {0.f, 0.f, 0.f, 0.f};

    const int wxor = (quad >> 1) << 4;            // P write rows quad*4+r: row bit3 = quad>>1
    const int rxor = ((l15 >> 3) & 1) << 4;       // P read row l15: row bit3 = l15>>3
    u16* pw = Ps + (w * 16 + quad * 4) * PSTR;
    const u16* pr = Ps + (w * 16 + l15) * PSTR;

    uint4 k0n, k1n, v0n, v1n;
#pragma unroll
    for (int kbi = 0; kbi < 8; kbi++) {
        // issue next block's staging loads early (hidden under this iteration)
        if (kbi + 1 < 8) {
            const u16* kbn = kbh + (size_t)kbl[kbi + 1] * BLK_ * QK2S_;
            const u16* vbn = vth + kbl[kbi + 1] * BLK_;
            k0n = *(const uint4*)(kbn + (size_t)r0s * QK2S_ + c8w * 8);
            k1n = *(const uint4*)(kbn + (size_t)r1s * QK2S_ + c8w * 8);
            v0n = *(const uint4*)(vbn + (size_t)r0s * S_ + c8w * 8);
            v1n = *(const uint4*)(vbn + (size_t)r1s * S_ + c8w * 8);
        }
        const u16* Kc = Ks + (kbi & 1) * 4096;
        const u16* Vc = Vs + (kbi & 1) * 4096;
        bf16x8 kf[4][2], vf[4][2];
#pragma unroll
        for (int c = 0; c < 4; c++)
#pragma unroll
            for (int ki = 0; ki < 2; ki++) {
                const int off = ((c * 16 + l15) * 8 + ((ki * 4 + quad) ^ xq)) * 8;
                kf[c][ki] = *(const bf16x8*)&Kc[off];
                vf[c][ki] = *(const bf16x8*)&Vc[off];
            }
        f32x4 s[4];
#pragma unroll
        for (int c = 0; c < 4; c++) s[c] = zero;
#pragma unroll
        for (int ki = 0; ki < 2; ki++)
#pragma unroll
            for (int c = 0; c < 4; c++)
                s[c] = __builtin_amdgcn_mfma_f32_16x16x32_bf16(qf[ki], kf[c][ki], s[c], 0, 0, 0);
        // constant-shift softmax numerator, in place in s
#pragma unroll
        for (int c = 0; c < 4; c++)
#pragma unroll
            for (int r = 0; r < 4; r++)
                s[c][r] = __expf(fmaf(s[c][r], 0.125f, -SOFT_SHIFT));
#pragma unroll
        for (int r = 0; r < 4; r++)
            ps[r] += (s[0][r] + s[1][r]) + (s[2][r] + s[3][r]);
        // P -> wave-private LDS (swizzled, static indexing, no barrier)
#pragma unroll
        for (int c = 0; c < 4; c++) {
            const int cbase = (c * 16 + l15) ^ wxor;
#pragma unroll
            for (int r = 0; r < 4; r++)
                pw[r * PSTR + cbase] = f2bf(s[c][r]);
        }
        // P fragments + PV (DS ops in-order per wave: reads see the writes)
#pragma unroll
        for (int ki = 0; ki < 2; ki++) {
            bf16x8 pf = *(const bf16x8*)(pr + ((ki * 32 + quad * 8) ^ rxor));
#pragma unroll
            for (int c = 0; c < 4; c++)
                o[c] = __builtin_amdgcn_mfma_f32_16x16x32_bf16(pf, vf[c][ki], o[c], 0, 0, 0);
        }
        // write next block into the other buffer; one barrier per iteration
        if (kbi + 1 < 8) {
            u16* Kn = Ks + ((kbi + 1) & 1) * 4096;
            u16* Vn = Vs + ((kbi + 1) & 1) * 4096;
            *(uint4*)&Kn[soff0] = k0n;  *(uint4*)&Kn[soff1] = k1n;
            *(uint4*)&Vn[soff0] = v0n;  *(uint4*)&Vn[soff1] = v1n;
            __syncthreads();
        }
    }
    // single final row-sum reduce across the 16 key lanes
#pragma unroll
    for (int r = 0; r < 4; r++) {
        float v = ps[r];
        v += __shfl_xor(v, 1, 16);
        v += __shfl_xor(v, 2, 16);
        v += __shfl_xor(v, 4, 16);
        v += __shfl_xor(v, 8, 16);
        l[r] = v;
    }
}

// ---------------------------------------------------------------- merged attention (sparse qblocks 1..62 + full-row chunks)

__global__ __launch_bounds__(256) void attn_kernel(
    const u16* __restrict__ qk, const u16* __restrict__ vtg,
    const int* __restrict__ rnd, u16* __restrict__ ctx,
    float* __restrict__ pctx, float* __restrict__ pl)
{
    __shared__ __align__(16) u16 Qs[4096];
    __shared__ __align__(16) u16 Ks[2 * 4096];
    __shared__ __align__(16) u16 Vs[2 * 4096];
    __shared__ __align__(16) u16 Ps[BLK_ * PSTR];

    // XCD-aware bijective swizzle: 1872 blocks = 8 XCDs x 234. Consecutive
    // logical ids (same (b,h), adjacent qblocks -> shared K/V) land on one XCD.
    const int hid = blockIdx.x + 78 * (blockIdx.y + H_ * blockIdx.z);
    const int lid = (hid & 7) * 234 + (hid >> 3);
    const int xk = lid % 78;
    const int yz = lid / 78;
    const int h = yz % H_;
    const int b = yz / H_;

    const int t = threadIdx.x;
    const int w = t >> 6, lane = t & 63;
    const int l15 = lane & 15, quad = lane >> 4;

    const bool sparse = (xk < 62);
    int qb, kbl[8], ci = 0;
    if (sparse) {
        qb = xk + 1;
        const int* rp = rnd + ((size_t)(h * NB_ + qb)) * R_;
        kbl[0] = 0; kbl[1] = qb - 1; kbl[2] = qb; kbl[3] = qb + 1;
        kbl[4] = NB_ - 1; kbl[5] = rp[0]; kbl[6] = rp[1]; kbl[7] = rp[2];
    } else {
        int e = xk - 62;
        int chunk = e & 7, qsel = e >> 3;
        qb = qsel ? (NB_ - 1) : 0;
#pragma unroll
        for (int i = 0; i < 8; i++) kbl[i] = chunk * 8 + i;
        ci = (((qsel * B_ + b) * H_ + h) * NCH_) + chunk;
    }

    const u16* qtile = qk + ((size_t)(b * S_ + qb * BLK_)) * QK2S_ + h * DH_;
    const u16* kbh   = qk + D_ + ((size_t)b * S_) * QK2S_ + h * DH_;
    const u16* vth   = vtg + ((size_t)(b * H_ + h) * DH_) * S_;

    f32x4 o[4]; float l[4];
    attn_core(qtile, kbh, vth, kbl, Qs, Ks, Vs, Ps, o, l);

    if (sparse) {
#pragma unroll
        for (int r = 0; r < 4; r++) {
            int row = w * 16 + quad * 4 + r;
            float inv = 1.f / l[r];
#pragma unroll
            for (int c = 0; c < 4; c++)
                ctx[((size_t)(b * S_ + qb * BLK_ + row)) * D_ + h * DH_ + c * 16 + l15] =
                    f2bf(o[c][r] * inv);
        }
    } else {
#pragma unroll
        for (int r = 0; r < 4; r++) {
            int row = w * 16 + quad * 4 + r;
#pragma unroll
            for (int c = 0; c < 4; c++)
                pctx[((size_t)ci * BLK_ + row) * DH_ + c * 16 + l15] = o[c][r];
            if (l15 == 0)
                pl[(size_t)ci * BLK_ + row] = l[r];
        }
    }
}

// combine: with constant shift, partials add directly (no max re-alignment)
__global__ __launch_bounds__(256) void attn_combine_kernel(
    const float* __restrict__ pctx, const float* __restrict__ pl,
    u16* __restrict__ ctx)
{
    const int qsel = blockIdx.x, h = blockIdx.y, b = blockIdx.z;
    const int qb = qsel ? (NB_ - 1) : 0;
    const int t = threadIdx.x;
    const int row = t >> 2, q4 = t & 3;
    const int cbase = ((qsel * B_ + b) * H_ + h) * NCH_;

    float L = 0.f;
#pragma unroll
    for (int c = 0; c < NCH_; c++) L += pl[(size_t)(cbase + c) * BLK_ + row];

    float acc[16];
#pragma unroll
    for (int j = 0; j < 16; j++) acc[j] = 0.f;
#pragma unroll
    for (int c = 0; c < NCH_; c++) {
        const float* src = pctx + ((size_t)(cbase + c) * BLK_ + row) * DH_ + q4 * 16;
#pragma unroll
        for (int jj = 0; jj < 4; jj++) {
            float4 f = *(const float4*)(src + jj * 4);
            acc[jj * 4 + 0] += f.x;
            acc[jj * 4 + 1] += f.y;
            acc[jj * 4 + 2] += f.z;
            acc[jj * 4 + 3] += f.w;
        }
    }
    float invL = 1.f / L;
    u16* dst = ctx + ((size_t)(b * S_ + qb * BLK_ + row)) * D_ + h * DH_ + q4 * 16;
    uint4 o0, o1;
#pragma unroll
    for (int g = 0; g < 8; g++) {
        unsigned lo = (unsigned)f2bf(acc[g * 2 + 0] * invL);
        unsigned hi = (unsigned)f2bf(acc[g * 2 + 1] * invL);
        unsigned pk = lo | (hi << 16);
        if (g < 4) (&o0.x)[g] = pk; else (&o1.x)[g - 4] = pk;
    }
    *(uint4*)dst = o0;
    *(uint4*)(dst + 8) = o1;
}

// ---------------------------------------------------------------- pooling + final dot

__global__ __launch_bounds__(256) void pool_kernel(
    const float* __restrict__ x, const float* __restrict__ fcw,
    float* __restrict__ acc)
{
    __shared__ float red[4];
    const int chunk = blockIdx.x, b = blockIdx.y;
    const int t = threadIdx.x;
    float s = 0.f;
    for (int sr = 0; sr < 128; sr++) {
        const float* xr = x + ((size_t)(b * S_ + chunk * 128 + sr)) * D_;
#pragma unroll
        for (int i = 0; i < 3; i++) {
            int d = t + i * 256;
            s += xr[d] * fcw[d];
        }
    }
    float tot = block_reduce_sum(s, red);
    if (t == 0) atomicAdd(&acc[b], tot);
}

__global__ void final_kernel(const float* __restrict__ acc,
                             const float* __restrict__ fcb,
                             float* __restrict__ out)
{
    if (threadIdx.x < B_) out[threadIdx.x] = acc[threadIdx.x] * (1.f / S_) + fcb[0];
}

// ---------------------------------------------------------------- launch

extern "C" void kernel_launch(void* const* d_in, const int* in_sizes, int n_in,
                              void* d_out, int out_size, void* d_ws, size_t ws_size,
                              hipStream_t stream)
{
    (void)in_sizes; (void)n_in; (void)out_size; (void)ws_size;
    const int*   ids  = (const int*)d_in[0];
    const int*   rnd  = (const int*)d_in[1];
    const float* etok = (const float*)d_in[2];
    const float* epos = (const float*)d_in[3];
    const float* lng  = (const float*)d_in[4];
    const float* lnb  = (const float*)d_in[5];
    const float* Wq   = (const float*)d_in[6];
    const float* bq   = (const float*)d_in[7];
    const float* Wk   = (const float*)d_in[8];
    const float* bk   = (const float*)d_in[9];
    const float* Wv   = (const float*)d_in[10];
    const float* bv   = (const float*)d_in[11];
    const float* Wo   = (const float*)d_in[12];
    const float* bo   = (const float*)d_in[13];
    const float* ln1g = (const float*)d_in[14];
    const float* ln1b = (const float*)d_in[15];
    const float* W1   = (const float*)d_in[16];
    const float* b1   = (const float*)d_in[17];
    const float* W2   = (const float*)d_in[18];
    const float* b2   = (const float*)d_in[19];
    const float* ln2g = (const float*)d_in[20];
    const float* ln2b = (const float*)d_in[21];
    const float* fcw  = (const float*)d_in[22];
    const float* fcb  = (const float*)d_in[23];
    float* out = (float*)d_out;

    // ---- workspace layout (~148 MB) ----
    const size_t MD = (size_t)M_ * D_;
    const size_t PCTX = (size_t)2 * B_ * H_ * NCH_ * BLK_ * DH_;
    const size_t PML  = (size_t)2 * B_ * H_ * NCH_ * BLK_;

    float* x     = (float*)d_ws;              // MD f32
    float* regB  = x + MD;                    // MD f32
    float* pctx  = regB + MD;                 // PCTX f32
    float* pl    = pctx + PCTX;               // PML f32
    u16*   qkb   = (u16*)(pl + PML);          // 2*MD bf16 (fused q|k per row)
    u16*   vtg   = qkb + 2 * MD;              // MD bf16, [B][H][DH][S]
    u16*   ctxb  = vtg + MD;                  // MD bf16
    u16*   ffhb  = qkb;                       // [M,FF] bf16, aliases qkb+vtg+ctxb
    u16*   xb    = ctxb + MD;                 // MD bf16
    u16*   wqkvb = xb + MD;                   // L*2304*768 bf16
    u16*   wob   = wqkvb + (size_t)L_ * 3 * D_ * D_;
    u16*   w1b   = wob + (size_t)L_ * D_ * D_;       // [L][FF][D]
    u16*   w2b   = w1b + (size_t)L_ * FF_ * D_;      // [L][D][FF]
    float* bqkv  = (float*)(w2b + (size_t)L_ * D_ * FF_);  // L*2304 f32
    float* acc   = bqkv + (size_t)L_ * 3 * D_;

    hipMemsetAsync(acc, 0, 2 * sizeof(float), stream);

    tcast_all_kernel<<<L_ * 6912, 256, 0, stream>>>(
        Wq, Wk, Wv, Wo, W1, W2, wqkvb, wob, w1b, w2b);
    bias_cat_kernel<<<(L_ * 3 * D_) / 256, 256, 0, stream>>>(bq, bk, bv, bqkv);
    embed_ln_kernel<<<M_, 256, 0, stream>>>(ids, etok, epos, lng, lnb, x, xb);

    dim3 gQKV(3 * D_ / 128, M_ / 128);     // (18, 64) = 1152 blocks (%8==0)
    dim3 g6(D_ / 128, M_ / 128);           // (6, 64)  = 384 blocks  (%8==0)
    dim3 gF(FF_ / 128, M_ / 128);          // (24, 64) = 1536 blocks (%8==0)
    for (int l = 0; l < L_; l++) {
        const size_t wo = (size_t)l * D_ * D_;
        const size_t vo = (size_t)l * D_;
        gemm_qkv_kernel<<<gQKV, 256, 0, stream>>>(
            xb, wqkvb + (size_t)l * 3 * D_ * D_, bqkv + (size_t)l * 3 * D_, qkb, vtg);
        attn_kernel<<<dim3(78, H_, B_), 256, 0, stream>>>(qkb, vtg, rnd, ctxb, pctx, pl);
        attn_combine_kernel<<<dim3(2, H_, B_), 256, 0, stream>>>(pctx, pl, ctxb);
        gemm_bf16_kernel<0, 0, D_, D_><<<g6, 256, 0, stream>>>(
            ctxb, wob + wo, bo + vo, regB);
        add_ln_kernel<0><<<M_, 256, 0, stream>>>(x, regB, nullptr, ln1g + vo, ln1b + vo, xb);
        gemm_bf16_kernel<1, 1, FF_, D_><<<gF, 256, 0, stream>>>(
            xb, w1b + (size_t)l * FF_ * D_, b1 + (size_t)l * FF_, ffhb);
        gemm_bf16_kernel<0, 0, D_, FF_><<<g6, 256, 0, stream>>>(
            ffhb, w2b + (size_t)l * D_ * FF_, b2 + vo, regB);
        add_ln_kernel<0><<<M_, 256, 0, stream>>>(x, regB, nullptr, ln2g + vo, ln2b + vo, xb);
    }
    pool_kernel<<<dim3(S_ / 128, B_), 256, 0, stream>>>(x, fcw, acc);
    final_kernel<<<1, 64, 0, stream>>>(acc, fcb, out);
}

// Round 13
// 723.120 us; speedup vs baseline: 1.2102x; 1.0086x over previous
//
#include <hip/hip_runtime.h>
#include <hip/hip_bf16.h>
#include <math.h>

// Problem constants (BigBird regressor, B=2, S=4096)
#define D_    768
#define H_    12
#define DH_   64
#define BLK_  64
#define L_    2
#define R_    3
#define B_    2
#define S_    4096
#define NB_   64          // S_/BLK_
#define M_    (B_*S_)     // 8192 tokens
#define FF_   (4*D_)      // 3072
#define NCH_  8           // split-K chunks for full-attention rows
#define QK2S_ (2*D_)      // fused q|k row stride (1536)

#define PSTR  72          // P LDS row stride (u16); 72*2=144B = 9*16 -> b128-aligned rows
#define SOFT_SHIFT 8.0f   // constant softmax shift (scores ~N(0,0.3); overflow needs s>100)

typedef unsigned short u16;
typedef __bf16 bf16x8 __attribute__((ext_vector_type(8)));
typedef float  f32x4  __attribute__((ext_vector_type(4)));

// GEMM LDS chunk address (16B units): grouped layout + XOR swizzle.
// Layout: [rowgrp(0..)][ca(0..3)][row16(0..15)] with row16 ^= ca<<1.
// - staging writes: conflict-free (verified r5: SQ_LDS_BANK_CONFLICT 21.2M->0)
// - fragment reads: 2-way (free).
// r13: REG-STAGING restored (r9 config). global_load_lds refuted twice on this
// workload: FETCH 43.8->63.2 MB with identical global address sets (r11/r12)
// -> the DMA path bypasses L1 and loses same-CU cross-block panel reuse.
#define GLDS(rowgrp, ca, row16) (((rowgrp) * 64 + (ca) * 16 + ((row16) ^ ((ca) << 1))) * 8)

// ---------------------------------------------------------------- helpers

__device__ inline float gelu_f(float x) {
    // exact tanh-gelu via exp: tanh(y) = 1 - 2/(e^{2y}+1)
    float y = 0.7978845608f * (x + 0.044715f * x * x * x);
    float e = __expf(2.f * y);
    float th = 1.f - 2.f / (e + 1.f);
    return 0.5f * x * (1.f + th);
}

__device__ inline u16 f2bf(float f) {
    union { __hip_bfloat16 h; u16 u; } cv;
    cv.h = __float2bfloat16(f);
    return cv.u;
}

__device__ inline float block_reduce_sum(float v, float* red) {
#pragma unroll
    for (int o = 32; o > 0; o >>= 1) v += __shfl_xor(v, o, 64);
    int wv = threadIdx.x >> 6;
    if ((threadIdx.x & 63) == 0) red[wv] = v;
    __syncthreads();
    float tot = red[0] + red[1] + red[2] + red[3];
    __syncthreads();
    return tot;
}

// XCD-aware bijective block swizzle (requires gx*gy % 8 == 0).
__device__ inline int xcd_lid() {
    const int hid = blockIdx.y * gridDim.x + blockIdx.x;
    const int chunk = (gridDim.x * gridDim.y) >> 3;
    return (hid & 7) * chunk + (hid >> 3);
}

// ---------------------------------------------------------------- fused weight transpose-cast

__global__ __launch_bounds__(256) void tcast_all_kernel(
    const float* __restrict__ Wq, const float* __restrict__ Wk,
    const float* __restrict__ Wv, const float* __restrict__ Wo,
    const float* __restrict__ W1, const float* __restrict__ W2,
    u16* __restrict__ wqkvb, u16* __restrict__ wob,
    u16* __restrict__ w1b, u16* __restrict__ w2b)
{
    __shared__ float tile[32][33];
    int idx = blockIdx.x;
    const int l = idx / 6912; idx -= l * 6912;
    const float* in; u16* outp; int K, N, x, y;
    if (idx < 2304) {
        int m = idx / 576, tt = idx % 576;
        x = tt % 24; y = tt / 24; K = D_; N = D_;
        const size_t wo = (size_t)l * D_ * D_;
        if (m == 0)      { in = Wq + wo; outp = wqkvb + (size_t)l * 3 * D_ * D_; }
        else if (m == 1) { in = Wk + wo; outp = wqkvb + (size_t)l * 3 * D_ * D_ + (size_t)D_ * D_; }
        else if (m == 2) { in = Wv + wo; outp = wqkvb + (size_t)l * 3 * D_ * D_ + (size_t)2 * D_ * D_; }
        else             { in = Wo + wo; outp = wob + wo; }
    } else if (idx < 4608) {
        int tt = idx - 2304;
        x = tt % 96; y = tt / 96; K = D_; N = FF_;
        in = W1 + (size_t)l * D_ * FF_; outp = w1b + (size_t)l * FF_ * D_;
    } else {
        int tt = idx - 4608;
        x = tt % 24; y = tt / 24; K = FF_; N = D_;
        in = W2 + (size_t)l * FF_ * D_; outp = w2b + (size_t)l * D_ * FF_;
    }
    const int n0 = x * 32, k0 = y * 32;
    const int tx = threadIdx.x & 31, ty = threadIdx.x >> 5;
#pragma unroll
    for (int p = 0; p < 4; p++)
        tile[ty + p * 8][tx] = in[(size_t)(k0 + ty + p * 8) * N + n0 + tx];
    __syncthreads();
#pragma unroll
    for (int p = 0; p < 4; p++)
        outp[(size_t)(n0 + ty + p * 8) * K + k0 + tx] = f2bf(tile[tx][ty + p * 8]);
}

__global__ __launch_bounds__(256) void bias_cat_kernel(
    const float* __restrict__ bq, const float* __restrict__ bk,
    const float* __restrict__ bv, float* __restrict__ o)
{
    int i = blockIdx.x * 256 + threadIdx.x;        // L_*3*D_ total
    int l = i / (3 * D_), c = i % (3 * D_);
    float v = (c < D_) ? bq[(size_t)l * D_ + c]
            : (c < 2 * D_) ? bk[(size_t)l * D_ + (c - D_)]
            : bv[(size_t)l * D_ + (c - 2 * D_)];
    o[i] = v;
}

// ---------------------------------------------------------------- embed+LN

__global__ __launch_bounds__(256) void embed_ln_kernel(
    const int* __restrict__ ids, const float* __restrict__ etok,
    const float* __restrict__ epos, const float* __restrict__ g,
    const float* __restrict__ bb, float* __restrict__ x, u16* __restrict__ xb)
{
    __shared__ float red[4];
    const int tok = blockIdx.x;
    const int s   = tok & (S_ - 1);
    const int id  = ids[tok];
    const int t   = threadIdx.x;
    float v[3];
    float sum = 0.f;
#pragma unroll
    for (int i = 0; i < 3; i++) {
        int d = t + i * 256;
        v[i] = etok[(size_t)id * D_ + d] + epos[(size_t)s * D_ + d];
        sum += v[i];
    }
    float mean = block_reduce_sum(sum, red) * (1.f / 768.f);
    float sq = 0.f;
#pragma unroll
    for (int i = 0; i < 3; i++) { float dd = v[i] - mean; sq += dd * dd; }
    float var = block_reduce_sum(sq, red) * (1.f / 768.f);
    float inv = rsqrtf(var + 1e-12f);
#pragma unroll
    for (int i = 0; i < 3; i++) {
        int d = t + i * 256;
        float o = (v[i] - mean) * inv * g[d] + bb[d];
        x[(size_t)tok * D_ + d] = o;
        xb[(size_t)tok * D_ + d] = f2bf(o);
    }
}

// ---------------------------------------------------------------- add + LN (in-place on x; also writes bf16 xb)

template <int YB>
__global__ __launch_bounds__(256) void add_ln_kernel(
    float* __restrict__ x, const float* __restrict__ y,
    const float* __restrict__ yb,
    const float* __restrict__ g, const float* __restrict__ bb,
    u16* __restrict__ xb)
{
    __shared__ float red[4];
    const int tok = blockIdx.x;
    const int t   = threadIdx.x;
    float* xr = x + (size_t)tok * D_;
    const float* yr = y + (size_t)tok * D_;
    float v[3];
    float sum = 0.f;
#pragma unroll
    for (int i = 0; i < 3; i++) {
        int d = t + i * 256;
        float bv = 0.f;
        if constexpr (YB) bv = yb[d];
        v[i] = xr[d] + yr[d] + bv;
        sum += v[i];
    }
    float mean = block_reduce_sum(sum, red) * (1.f / 768.f);
    float sq = 0.f;
#pragma unroll
    for (int i = 0; i < 3; i++) { float dd = v[i] - mean; sq += dd * dd; }
    float var = block_reduce_sum(sq, red) * (1.f / 768.f);
    float inv = rsqrtf(var + 1e-12f);
#pragma unroll
    for (int i = 0; i < 3; i++) {
        int d = t + i * 256;
        float o = (v[i] - mean) * inv * g[d] + bb[d];
        xr[d] = o;
        xb[(size_t)tok * D_ + d] = f2bf(o);
    }
}

// ---------------------------------------------------------------- bf16 MFMA GEMM (128x128 tile)
// Double-buffered LDS, ONE barrier per K-step; GLDS swizzle; XCD swizzle.
// Reg-staging (r9 config — best verified: ff1 70.5us, FETCH 43.8MB).

template <int ACT, int OBF, int NN, int KK>
__global__ __launch_bounds__(256) void gemm_bf16_kernel(
    const u16* __restrict__ A, const u16* __restrict__ Wt,
    const float* __restrict__ bias, void* __restrict__ Cv)
{
    __shared__ __align__(16) u16 As[2][4096];   // 128x32 bf16 x2
    __shared__ __align__(16) u16 Bs[2][4096];
    const int t = threadIdx.x;
    const int gx = gridDim.x;
    const int lid = xcd_lid();
    const int row0 = (lid / gx) * 128, col0 = (lid % gx) * 128;
    const int w = t >> 6, lane = t & 63;
    const int wr = w >> 1, wc = w & 1;
    const int i16 = lane & 15, qd = lane >> 4;

    const f32x4 zero = {0.f, 0.f, 0.f, 0.f};
    f32x4 acc[4][4];
#pragma unroll
    for (int r = 0; r < 4; r++)
#pragma unroll
        for (int c = 0; c < 4; c++) acc[r][c] = zero;

    const int e0 = t, e1 = t + 256;
    const int ra0 = e0 >> 2, ca0 = e0 & 3;
    const int ra1 = e1 >> 2, ca1 = e1 & 3;
    const int lds0 = GLDS(ra0 >> 4, ca0, ra0 & 15);
    const int lds1 = GLDS(ra1 >> 4, ca1, ra1 & 15);

    uint4 a0, a1, b0, b1;
    a0 = *(const uint4*)(A + (size_t)(row0 + ra0) * KK + ca0 * 8);
    a1 = *(const uint4*)(A + (size_t)(row0 + ra1) * KK + ca1 * 8);
    b0 = *(const uint4*)(Wt + (size_t)(col0 + ra0) * KK + ca0 * 8);
    b1 = *(const uint4*)(Wt + (size_t)(col0 + ra1) * KK + ca1 * 8);
    *(uint4*)&As[0][lds0] = a0;
    *(uint4*)&As[0][lds1] = a1;
    *(uint4*)&Bs[0][lds0] = b0;
    *(uint4*)&Bs[0][lds1] = b1;
    __syncthreads();

#pragma unroll 2
    for (int k0 = 0; k0 < KK; k0 += 32) {
        const int buf = (k0 >> 5) & 1;
        const bool more = (k0 + 32 < KK);
        if (more) {                        // issue next-tile loads early
            int kn = k0 + 32;
            a0 = *(const uint4*)(A + (size_t)(row0 + ra0) * KK + kn + ca0 * 8);
            a1 = *(const uint4*)(A + (size_t)(row0 + ra1) * KK + kn + ca1 * 8);
            b0 = *(const uint4*)(Wt + (size_t)(col0 + ra0) * KK + kn + ca0 * 8);
            b1 = *(const uint4*)(Wt + (size_t)(col0 + ra1) * KK + kn + ca1 * 8);
        }
        bf16x8 af[4], bfr[4];
#pragma unroll
        for (int r = 0; r < 4; r++)
            af[r] = *(const bf16x8*)&As[buf][GLDS(wr * 4 + r, qd, i16)];
#pragma unroll
        for (int c = 0; c < 4; c++)
            bfr[c] = *(const bf16x8*)&Bs[buf][GLDS(wc * 4 + c, qd, i16)];
#pragma unroll
        for (int r = 0; r < 4; r++)
#pragma unroll
            for (int c = 0; c < 4; c++)
                acc[r][c] = __builtin_amdgcn_mfma_f32_16x16x32_bf16(af[r], bfr[c], acc[r][c], 0, 0, 0);
        if (more) {                        // write next tile into other buffer
            *(uint4*)&As[buf ^ 1][lds0] = a0;
            *(uint4*)&As[buf ^ 1][lds1] = a1;
            *(uint4*)&Bs[buf ^ 1][lds0] = b0;
            *(uint4*)&Bs[buf ^ 1][lds1] = b1;
            __syncthreads();
        }
    }

#pragma unroll
    for (int c = 0; c < 4; c++) {
        int colg = col0 + wc * 64 + c * 16 + i16;
        float bsv = bias[colg];
#pragma unroll
        for (int r = 0; r < 4; r++) {
            int rowb = row0 + wr * 64 + r * 16 + qd * 4;
#pragma unroll
            for (int p = 0; p < 4; p++) {
                float val = acc[r][c][p] + bsv;
                if (ACT == 1) val = gelu_f(val);
                if (OBF == 1)
                    ((u16*)Cv)[(size_t)(rowb + p) * NN + colg] = f2bf(val);
                else
                    ((float*)Cv)[(size_t)(rowb + p) * NN + colg] = val;
            }
        }
    }
}

// ---------------------------------------------------------------- fused QKV GEMM (NN=2304, KK=768)
// Q,K -> fused [M,1536] bf16; V -> transposed global [B][H][DH][S] bf16

__global__ __launch_bounds__(256) void gemm_qkv_kernel(
    const u16* __restrict__ A, const u16* __restrict__ Wt,
    const float* __restrict__ bias, u16* __restrict__ qk, u16* __restrict__ vtg)
{
    __shared__ __align__(16) u16 As[2][4096];
    __shared__ __align__(16) u16 Bs[2][4096];
    const int t = threadIdx.x;
    const int gx = gridDim.x;
    const int lid = xcd_lid();
    const int row0 = (lid / gx) * 128, col0 = (lid % gx) * 128;
    const int w = t >> 6, lane = t & 63;
    const int wr = w >> 1, wc = w & 1;
    const int i16 = lane & 15, qd = lane >> 4;

    const f32x4 zero = {0.f, 0.f, 0.f, 0.f};
    f32x4 acc[4][4];
#pragma unroll
    for (int r = 0; r < 4; r++)
#pragma unroll
        for (int c = 0; c < 4; c++) acc[r][c] = zero;

    const int e0 = t, e1 = t + 256;
    const int ra0 = e0 >> 2, ca0 = e0 & 3;
    const int ra1 = e1 >> 2, ca1 = e1 & 3;
    const int lds0 = GLDS(ra0 >> 4, ca0, ra0 & 15);
    const int lds1 = GLDS(ra1 >> 4, ca1, ra1 & 15);

    uint4 a0, a1, b0, b1;
    a0 = *(const uint4*)(A + (size_t)(row0 + ra0) * D_ + ca0 * 8);
    a1 = *(const uint4*)(A + (size_t)(row0 + ra1) * D_ + ca1 * 8);
    b0 = *(const uint4*)(Wt + (size_t)(col0 + ra0) * D_ + ca0 * 8);
    b1 = *(const uint4*)(Wt + (size_t)(col0 + ra1) * D_ + ca1 * 8);
    *(uint4*)&As[0][lds0] = a0;
    *(uint4*)&As[0][lds1] = a1;
    *(uint4*)&Bs[0][lds0] = b0;
    *(uint4*)&Bs[0][lds1] = b1;
    __syncthreads();

#pragma unroll 2
    for (int k0 = 0; k0 < D_; k0 += 32) {
        const int buf = (k0 >> 5) & 1;
        const bool more = (k0 + 32 < D_);
        if (more) {
            int kn = k0 + 32;
            a0 = *(const uint4*)(A + (size_t)(row0 + ra0) * D_ + kn + ca0 * 8);
            a1 = *(const uint4*)(A + (size_t)(row0 + ra1) * D_ + kn + ca1 * 8);
            b0 = *(const uint4*)(Wt + (size_t)(col0 + ra0) * D_ + kn + ca0 * 8);
            b1 = *(const uint4*)(Wt + (size_t)(col0 + ra1) * D_ + kn + ca1 * 8);
        }
        bf16x8 af[4], bfr[4];
#pragma unroll
        for (int r = 0; r < 4; r++)
            af[r] = *(const bf16x8*)&As[buf][GLDS(wr * 4 + r, qd, i16)];
#pragma unroll
        for (int c = 0; c < 4; c++)
            bfr[c] = *(const bf16x8*)&Bs[buf][GLDS(wc * 4 + c, qd, i16)];
#pragma unroll
        for (int r = 0; r < 4; r++)
#pragma unroll
            for (int c = 0; c < 4; c++)
                acc[r][c] = __builtin_amdgcn_mfma_f32_16x16x32_bf16(af[r], bfr[c], acc[r][c], 0, 0, 0);
        if (more) {
            *(uint4*)&As[buf ^ 1][lds0] = a0;
            *(uint4*)&As[buf ^ 1][lds1] = a1;
            *(uint4*)&Bs[buf ^ 1][lds0] = b0;
            *(uint4*)&Bs[buf ^ 1][lds1] = b1;
            __syncthreads();
        }
    }

#pragma unroll
    for (int c = 0; c < 4; c++) {
        int colg = col0 + wc * 64 + c * 16 + i16;
        float bsv = bias[colg];
        if (colg < QK2S_) {                          // Q|K region
#pragma unroll
            for (int r = 0; r < 4; r++) {
                int rowb = row0 + wr * 64 + r * 16 + qd * 4;
#pragma unroll
                for (int p = 0; p < 4; p++)
                    qk[(size_t)(rowb + p) * QK2S_ + colg] = f2bf(acc[r][c][p] + bsv);
            }
        } else {                                     // V region -> transposed [B][H][DH][S]
            int cv = colg - QK2S_;
            int h = cv >> 6, d = cv & 63;
#pragma unroll
            for (int r = 0; r < 4; r++) {
                int rowb = row0 + wr * 64 + r * 16 + qd * 4;
                int bb = rowb >> 12, ss = rowb & (S_ - 1);
                uint2 o;
                o.x = (unsigned)f2bf(acc[r][c][0] + bsv) | ((unsigned)f2bf(acc[r][c][1] + bsv) << 16);
                o.y = (unsigned)f2bf(acc[r][c][2] + bsv) | ((unsigned)f2bf(acc[r][c][3] + bsv) << 16);
                *(uint2*)(vtg + (((size_t)(bb * H_ + h) * DH_ + d) * S_ + ss)) = o;
            }
        }
    }
}

// ---------------------------------------------------------------- MFMA attention core (coalesced cooperative staging)
// Each 64B line of K/V/Q fetched from global EXACTLY ONCE per block (8
// consecutive lanes cover one 128B row-segment), staged into XOR-swizzled LDS;
// all 4 waves read MFMA fragments from LDS. Double-buffered K/V, ONE barrier
// per key-block; loads issue at iteration top, ds_write after compute.
// P = exp(s/8 - SOFT_SHIFT); Ps is wave-private (in-order DS -> no barrier).
// O and l are unnormalized-but-consistent; caller divides.

__device__ inline void attn_core(
    const u16* __restrict__ qtile,   // qk + (b*S + qb*64)*1536 + h*64
    const u16* __restrict__ kbh,     // qk + 768 + b*S*1536 + h*64
    const u16* __restrict__ vth,     // vtg + (b*H + h)*64*S
    const int* kbl,                  // 8 key-block indices
    u16* Qs, u16* Ks, u16* Vs, u16* Ps,
    f32x4 (&o)[4], float (&l)[4])
{
    const int t = threadIdx.x;
    const int w = t >> 6, lane = t & 63;
    const int l15 = lane & 15, quad = lane >> 4;

    // staging mapping: thread covers 16B chunk c8w of rows r0 (li=0) / r1 (li=1)
    const int rsub = lane >> 3;            // 0..7
    const int c8w  = lane & 7;             // 0..7
    const int r0s  = w * 8 + rsub;         // rows 0..31 across waves
    const int r1s  = r0s + 32;             // rows 32..63
    const int soff0 = (r0s * 8 + (c8w ^ (r0s & 7))) * 8;   // u16 index
    const int soff1 = (r1s * 8 + (c8w ^ (r1s & 7))) * 8;

    // ---- prologue: stage Q + first K/V block (each line fetched once)
    {
        uint4 q0 = *(const uint4*)(qtile + (size_t)r0s * QK2S_ + c8w * 8);
        uint4 q1 = *(const uint4*)(qtile + (size_t)r1s * QK2S_ + c8w * 8);
        const u16* kb0 = kbh + (size_t)kbl[0] * BLK_ * QK2S_;
        const u16* vb0 = vth + kbl[0] * BLK_;
        uint4 k0 = *(const uint4*)(kb0 + (size_t)r0s * QK2S_ + c8w * 8);
        uint4 k1 = *(const uint4*)(kb0 + (size_t)r1s * QK2S_ + c8w * 8);
        uint4 v0 = *(const uint4*)(vb0 + (size_t)r0s * S_ + c8w * 8);
        uint4 v1 = *(const uint4*)(vb0 + (size_t)r1s * S_ + c8w * 8);
        *(uint4*)&Qs[soff0] = q0;  *(uint4*)&Qs[soff1] = q1;
        *(uint4*)&Ks[soff0] = k0;  *(uint4*)&Ks[soff1] = k1;
        *(uint4*)&Vs[soff0] = v0;  *(uint4*)&Vs[soff1] = v1;
    }
    __syncthreads();

    // Q fragments: row w*16+l15, chunk ki*4+quad (swizzled) -> regs, once
    const int xq = l15 & 7;
    bf16x8 qf[2];
#pragma unroll
    for (int ki = 0; ki < 2; ki++)
        qf[ki] = *(const bf16x8*)&Qs[((w * 16 + l15) * 8 + ((ki * 4 + quad) ^ xq)) * 8];

    const f32x4 zero = {0.f, 0.f, 0.f, 0.f};
#pragma unroll
    for (int c = 0; c < 4; c++) o[c] = zero;
    float ps[4] = {0.f, 0.f, 0.f, 0.f};

    const int wxor = (quad >> 1) << 4;            // P write rows quad*4+r: row bit3 = quad>>1
    const int rxor = ((l15 >> 3) & 1) << 4;       // P read row l15: row bit3 = l15>>3
    u16* pw = Ps + (w * 16 + quad * 4) * PSTR;
    const u16* pr = Ps + (w * 16 + l15) * PSTR;

    uint4 k0n, k1n, v0n, v1n;
#pragma unroll
    for (int kbi = 0; kbi < 8; kbi++) {
        // issue next block's staging loads early (hidden under this iteration)
        if (kbi + 1 < 8) {
            const u16* kbn = kbh + (size_t)kbl[kbi + 1] * BLK_ * QK2S_;
            const u16* vbn = vth + kbl[kbi + 1] * BLK_;
            k0n = *(const uint4*)(kbn + (size_t)r0s * QK2S_ + c8w * 8);
            k1n = *(const uint4*)(kbn + (size_t)r1s * QK2S_ + c8w * 8);
            v0n = *(const uint4*)(vbn + (size_t)r0s * S_ + c8w * 8);
            v1n = *(const uint4*)(vbn + (size_t)r1s * S_ + c8w * 8);
        }
        const u16* Kc = Ks + (kbi & 1) * 4096;
        const u16* Vc = Vs + (kbi & 1) * 4096;
        bf16x8 kf[4][2], vf[4][2];
#pragma unroll
        for (int c = 0; c < 4; c++)
#pragma unroll
            for (int ki = 0; ki < 2; ki++) {
                const int off = ((c * 16 + l15) * 8 + ((ki * 4 + quad) ^ xq)) * 8;
                kf[c][ki] = *(const bf16x8*)&Kc[off];
                vf[c][ki] = *(const bf16x8*)&Vc[off];
            }
        f32x4 s[4];
#pragma unroll
        for (int c = 0; c < 4; c++) s[c] = zero;
#pragma unroll
        for (int ki = 0; ki < 2; ki++)
#pragma unroll
            for (int c = 0; c < 4; c++)
                s[c] = __builtin_amdgcn_mfma_f32_16x16x32_bf16(qf[ki], kf[c][ki], s[c], 0, 0, 0);
        // constant-shift softmax numerator, in place in s
#pragma unroll
        for (int c = 0; c < 4; c++)
#pragma unroll
            for (int r = 0; r < 4; r++)
                s[c][r] = __expf(fmaf(s[c][r], 0.125f, -SOFT_SHIFT));
#pragma unroll
        for (int r = 0; r < 4; r++)
            ps[r] += (s[0][r] + s[1][r]) + (s[2][r] + s[3][r]);
        // P -> wave-private LDS (swizzled, static indexing, no barrier)
#pragma unroll
        for (int c = 0; c < 4; c++) {
            const int cbase = (c * 16 + l15) ^ wxor;
#pragma unroll
            for (int r = 0; r < 4; r++)
                pw[r * PSTR + cbase] = f2bf(s[c][r]);
        }
        // P fragments + PV (DS ops in-order per wave: reads see the writes)
#pragma unroll
        for (int ki = 0; ki < 2; ki++) {
            bf16x8 pf = *(const bf16x8*)(pr + ((ki * 32 + quad * 8) ^ rxor));
#pragma unroll
            for (int c = 0; c < 4; c++)
                o[c] = __builtin_amdgcn_mfma_f32_16x16x32_bf16(pf, vf[c][ki], o[c], 0, 0, 0);
        }
        // write next block into the other buffer; one barrier per iteration
        if (kbi + 1 < 8) {
            u16* Kn = Ks + ((kbi + 1) & 1) * 4096;
            u16* Vn = Vs + ((kbi + 1) & 1) * 4096;
            *(uint4*)&Kn[soff0] = k0n;  *(uint4*)&Kn[soff1] = k1n;
            *(uint4*)&Vn[soff0] = v0n;  *(uint4*)&Vn[soff1] = v1n;
            __syncthreads();
        }
    }
    // single final row-sum reduce across the 16 key lanes
#pragma unroll
    for (int r = 0; r < 4; r++) {
        float v = ps[r];
        v += __shfl_xor(v, 1, 16);
        v += __shfl_xor(v, 2, 16);
        v += __shfl_xor(v, 4, 16);
        v += __shfl_xor(v, 8, 16);
        l[r] = v;
    }
}

// ---------------------------------------------------------------- merged attention (sparse qblocks 1..62 + full-row chunks)

__global__ __launch_bounds__(256) void attn_kernel(
    const u16* __restrict__ qk, const u16* __restrict__ vtg,
    const int* __restrict__ rnd, u16* __restrict__ ctx,
    float* __restrict__ pctx, float* __restrict__ pl)
{
    __shared__ __align__(16) u16 Qs[4096];
    __shared__ __align__(16) u16 Ks[2 * 4096];
    __shared__ __align__(16) u16 Vs[2 * 4096];
    __shared__ __align__(16) u16 Ps[BLK_ * PSTR];

    // XCD-aware bijective swizzle: 1872 blocks = 8 XCDs x 234. Consecutive
    // logical ids (same (b,h), adjacent qblocks -> shared K/V) land on one XCD.
    const int hid = blockIdx.x + 78 * (blockIdx.y + H_ * blockIdx.z);
    const int lid = (hid & 7) * 234 + (hid >> 3);
    const int xk = lid % 78;
    const int yz = lid / 78;
    const int h = yz % H_;
    const int b = yz / H_;

    const int t = threadIdx.x;
    const int w = t >> 6, lane = t & 63;
    const int l15 = lane & 15, quad = lane >> 4;

    const bool sparse = (xk < 62);
    int qb, kbl[8], ci = 0;
    if (sparse) {
        qb = xk + 1;
        const int* rp = rnd + ((size_t)(h * NB_ + qb)) * R_;
        kbl[0] = 0; kbl[1] = qb - 1; kbl[2] = qb; kbl[3] = qb + 1;
        kbl[4] = NB_ - 1; kbl[5] = rp[0]; kbl[6] = rp[1]; kbl[7] = rp[2];
    } else {
        int e = xk - 62;
        int chunk = e & 7, qsel = e >> 3;
        qb = qsel ? (NB_ - 1) : 0;
#pragma unroll
        for (int i = 0; i < 8; i++) kbl[i] = chunk * 8 + i;
        ci = (((qsel * B_ + b) * H_ + h) * NCH_) + chunk;
    }

    const u16* qtile = qk + ((size_t)(b * S_ + qb * BLK_)) * QK2S_ + h * DH_;
    const u16* kbh   = qk + D_ + ((size_t)b * S_) * QK2S_ + h * DH_;
    const u16* vth   = vtg + ((size_t)(b * H_ + h) * DH_) * S_;

    f32x4 o[4]; float l[4];
    attn_core(qtile, kbh, vth, kbl, Qs, Ks, Vs, Ps, o, l);

    if (sparse) {
#pragma unroll
        for (int r = 0; r < 4; r++) {
            int row = w * 16 + quad * 4 + r;
            float inv = 1.f / l[r];
#pragma unroll
            for (int c = 0; c < 4; c++)
                ctx[((size_t)(b * S_ + qb * BLK_ + row)) * D_ + h * DH_ + c * 16 + l15] =
                    f2bf(o[c][r] * inv);
        }
    } else {
#pragma unroll
        for (int r = 0; r < 4; r++) {
            int row = w * 16 + quad * 4 + r;
#pragma unroll
            for (int c = 0; c < 4; c++)
                pctx[((size_t)ci * BLK_ + row) * DH_ + c * 16 + l15] = o[c][r];
            if (l15 == 0)
                pl[(size_t)ci * BLK_ + row] = l[r];
        }
    }
}

// combine: with constant shift, partials add directly (no max re-alignment)
__global__ __launch_bounds__(256) void attn_combine_kernel(
    const float* __restrict__ pctx, const float* __restrict__ pl,
    u16* __restrict__ ctx)
{
    const int qsel = blockIdx.x, h = blockIdx.y, b = blockIdx.z;
    const int qb = qsel ? (NB_ - 1) : 0;
    const int t = threadIdx.x;
    const int row = t >> 2, q4 = t & 3;
    const int cbase = ((qsel * B_ + b) * H_ + h) * NCH_;

    float L = 0.f;
#pragma unroll
    for (int c = 0; c < NCH_; c++) L += pl[(size_t)(cbase + c) * BLK_ + row];

    float acc[16];
#pragma unroll
    for (int j = 0; j < 16; j++) acc[j] = 0.f;
#pragma unroll
    for (int c = 0; c < NCH_; c++) {
        const float* src = pctx + ((size_t)(cbase + c) * BLK_ + row) * DH_ + q4 * 16;
#pragma unroll
        for (int jj = 0; jj < 4; jj++) {
            float4 f = *(const float4*)(src + jj * 4);
            acc[jj * 4 + 0] += f.x;
            acc[jj * 4 + 1] += f.y;
            acc[jj * 4 + 2] += f.z;
            acc[jj * 4 + 3] += f.w;
        }
    }
    float invL = 1.f / L;
    u16* dst = ctx + ((size_t)(b * S_ + qb * BLK_ + row)) * D_ + h * DH_ + q4 * 16;
    uint4 o0, o1;
#pragma unroll
    for (int g = 0; g < 8; g++) {
        unsigned lo = (unsigned)f2bf(acc[g * 2 + 0] * invL);
        unsigned hi = (unsigned)f2bf(acc[g * 2 + 1] * invL);
        unsigned pk = lo | (hi << 16);
        if (g < 4) (&o0.x)[g] = pk; else (&o1.x)[g - 4] = pk;
    }
    *(uint4*)dst = o0;
    *(uint4*)(dst + 8) = o1;
}

// ---------------------------------------------------------------- pooling + final dot

__global__ __launch_bounds__(256) void pool_kernel(
    const float* __restrict__ x, const float* __restrict__ fcw,
    float* __restrict__ acc)
{
    __shared__ float red[4];
    const int chunk = blockIdx.x, b = blockIdx.y;
    const int t = threadIdx.x;
    float s = 0.f;
    for (int sr = 0; sr < 128; sr++) {
        const float* xr = x + ((size_t)(b * S_ + chunk * 128 + sr)) * D_;
#pragma unroll
        for (int i = 0; i < 3; i++) {
            int d = t + i * 256;
            s += xr[d] * fcw[d];
        }
    }
    float tot = block_reduce_sum(s, red);
    if (t == 0) atomicAdd(&acc[b], tot);
}

__global__ void final_kernel(const float* __restrict__ acc,
                             const float* __restrict__ fcb,
                             float* __restrict__ out)
{
    if (threadIdx.x < B_) out[threadIdx.x] = acc[threadIdx.x] * (1.f / S_) + fcb[0];
}

// ---------------------------------------------------------------- launch

extern "C" void kernel_launch(void* const* d_in, const int* in_sizes, int n_in,
                              void* d_out, int out_size, void* d_ws, size_t ws_size,
                              hipStream_t stream)
{
    (void)in_sizes; (void)n_in; (void)out_size; (void)ws_size;
    const int*   ids  = (const int*)d_in[0];
    const int*   rnd  = (const int*)d_in[1];
    const float* etok = (const float*)d_in[2];
    const float* epos = (const float*)d_in[3];
    const float* lng  = (const float*)d_in[4];
    const float* lnb  = (const float*)d_in[5];
    const float* Wq   = (const float*)d_in[6];
    const float* bq   = (const float*)d_in[7];
    const float* Wk   = (const float*)d_in[8];
    const float* bk   = (const float*)d_in[9];
    const float* Wv   = (const float*)d_in[10];
    const float* bv   = (const float*)d_in[11];
    const float* Wo   = (const float*)d_in[12];
    const float* bo   = (const float*)d_in[13];
    const float* ln1g = (const float*)d_in[14];
    const float* ln1b = (const float*)d_in[15];
    const float* W1   = (const float*)d_in[16];
    const float* b1   = (const float*)d_in[17];
    const float* W2   = (const float*)d_in[18];
    const float* b2   = (const float*)d_in[19];
    const float* ln2g = (const float*)d_in[20];
    const float* ln2b = (const float*)d_in[21];
    const float* fcw  = (const float*)d_in[22];
    const float* fcb  = (const float*)d_in[23];
    float* out = (float*)d_out;

    // ---- workspace layout (~148 MB) ----
    const size_t MD = (size_t)M_ * D_;
    const size_t PCTX = (size_t)2 * B_ * H_ * NCH_ * BLK_ * DH_;
    const size_t PML  = (size_t)2 * B_ * H_ * NCH_ * BLK_;

    float* x     = (float*)d_ws;              // MD f32
    float* regB  = x + MD;                    // MD f32
    float* pctx  = regB + MD;                 // PCTX f32
    float* pl    = pctx + PCTX;               // PML f32
    u16*   qkb   = (u16*)(pl + PML);          // 2*MD bf16 (fused q|k per row)
    u16*   vtg   = qkb + 2 * MD;              // MD bf16, [B][H][DH][S]
    u16*   ctxb  = vtg + MD;                  // MD bf16
    u16*   ffhb  = qkb;                       // [M,FF] bf16, aliases qkb+vtg+ctxb
    u16*   xb    = ctxb + MD;                 // MD bf16
    u16*   wqkvb = xb + MD;                   // L*2304*768 bf16
    u16*   wob   = wqkvb + (size_t)L_ * 3 * D_ * D_;
    u16*   w1b   = wob + (size_t)L_ * D_ * D_;       // [L][FF][D]
    u16*   w2b   = w1b + (size_t)L_ * FF_ * D_;      // [L][D][FF]
    float* bqkv  = (float*)(w2b + (size_t)L_ * D_ * FF_);  // L*2304 f32
    float* acc   = bqkv + (size_t)L_ * 3 * D_;

    hipMemsetAsync(acc, 0, 2 * sizeof(float), stream);

    tcast_all_kernel<<<L_ * 6912, 256, 0, stream>>>(
        Wq, Wk, Wv, Wo, W1, W2, wqkvb, wob, w1b, w2b);
    bias_cat_kernel<<<(L_ * 3 * D_) / 256, 256, 0, stream>>>(bq, bk, bv, bqkv);
    embed_ln_kernel<<<M_, 256, 0, stream>>>(ids, etok, epos, lng, lnb, x, xb);

    dim3 gQKV(3 * D_ / 128, M_ / 128);     // (18, 64) = 1152 blocks (%8==0)
    dim3 g6(D_ / 128, M_ / 128);           // (6, 64)  = 384 blocks  (%8==0)
    dim3 gF(FF_ / 128, M_ / 128);          // (24, 64) = 1536 blocks (%8==0)
    for (int l = 0; l < L_; l++) {
        const size_t wo = (size_t)l * D_ * D_;
        const size_t vo = (size_t)l * D_;
        gemm_qkv_kernel<<<gQKV, 256, 0, stream>>>(
            xb, wqkvb + (size_t)l * 3 * D_ * D_, bqkv + (size_t)l * 3 * D_, qkb, vtg);
        attn_kernel<<<dim3(78, H_, B_), 256, 0, stream>>>(qkb, vtg, rnd, ctxb, pctx, pl);
        attn_combine_kernel<<<dim3(2, H_, B_), 256, 0, stream>>>(pctx, pl, ctxb);
        gemm_bf16_kernel<0, 0, D_, D_><<<g6, 256, 0, stream>>>(
            ctxb, wob + wo, bo + vo, regB);
        add_ln_kernel<0><<<M_, 256, 0, stream>>>(x, regB, nullptr, ln1g + vo, ln1b + vo, xb);
        gemm_bf16_kernel<1, 1, FF_, D_><<<gF, 256, 0, stream>>>(
            xb, w1b + (size_t)l * FF_ * D_, b1 + (size_t)l * FF_, ffhb);
        gemm_bf16_kernel<0, 0, D_, FF_><<<g6, 256, 0, stream>>>(
            ffhb, w2b + (size_t)l * D_ * FF_, b2 + vo, regB);
        add_ln_kernel<0><<<M_, 256, 0, stream>>>(x, regB, nullptr, ln2g + vo, ln2b + vo, xb);
    }
    pool_kernel<<<dim3(S_ / 128, B_), 256, 0, stream>>>(x, fcw, acc);
    final_kernel<<<1, 64, 0, stream>>>(acc, fcb, out);
}

// Round 14
// 690.187 us; speedup vs baseline: 1.2680x; 1.0477x over previous
//
#include <hip/hip_runtime.h>
#include <hip/hip_bf16.h>
#include <math.h>

// Problem constants (BigBird regressor, B=2, S=4096)
#define D_    768
#define H_    12
#define DH_   64
#define BLK_  64
#define L_    2
#define R_    3
#define B_    2
#define S_    4096
#define NB_   64          // S_/BLK_
#define M_    (B_*S_)     // 8192 tokens
#define FF_   (4*D_)      // 3072
#define NCH_  8           // split-K chunks for full-attention rows
#define QK2S_ (2*D_)      // fused q|k row stride (1536)

#define PSTR  72          // P LDS row stride (u16); 72*2=144B = 9*16 -> b128-aligned rows
#define SOFT_SHIFT 8.0f   // constant softmax shift (scores ~N(0,0.3); overflow needs s>100)

typedef unsigned short u16;
typedef __bf16 bf16x8 __attribute__((ext_vector_type(8)));
typedef float  f32x4  __attribute__((ext_vector_type(4)));

// GEMM LDS chunk address (16B units): grouped layout + XOR swizzle.
// Layout: [rowgrp(0..)][ca(0..3)][row16(0..15)] with row16 ^= ca<<1.
// - staging writes: conflict-free (verified r5: SQ_LDS_BANK_CONFLICT 21.2M->0)
// - fragment reads: 2-way (free).
// Reg-staging only: global_load_lds refuted twice (r11/r12 — L1 bypass,
// FETCH 43.8->63.2 MB on identical address sets).
#define GLDS(rowgrp, ca, row16) (((rowgrp) * 64 + (ca) * 16 + ((row16) ^ ((ca) << 1))) * 8)

// ---------------------------------------------------------------- helpers

__device__ inline float gelu_f(float x) {
    // exact tanh-gelu via exp: tanh(y) = 1 - 2/(e^{2y}+1)
    float y = 0.7978845608f * (x + 0.044715f * x * x * x);
    float e = __expf(2.f * y);
    float th = 1.f - 2.f / (e + 1.f);
    return 0.5f * x * (1.f + th);
}

__device__ inline u16 f2bf(float f) {
    union { __hip_bfloat16 h; u16 u; } cv;
    cv.h = __float2bfloat16(f);
    return cv.u;
}

__device__ inline float block_reduce_sum(float v, float* red) {
#pragma unroll
    for (int o = 32; o > 0; o >>= 1) v += __shfl_xor(v, o, 64);
    int wv = threadIdx.x >> 6;
    if ((threadIdx.x & 63) == 0) red[wv] = v;
    __syncthreads();
    float tot = red[0] + red[1] + red[2] + red[3];
    __syncthreads();
    return tot;
}

// XCD-aware bijective block swizzle (requires gx*gy % 8 == 0).
__device__ inline int xcd_lid() {
    const int hid = blockIdx.y * gridDim.x + blockIdx.x;
    const int chunk = (gridDim.x * gridDim.y) >> 3;
    return (hid & 7) * chunk + (hid >> 3);
}

// ---------------------------------------------------------------- fused weight transpose-cast

__global__ __launch_bounds__(256) void tcast_all_kernel(
    const float* __restrict__ Wq, const float* __restrict__ Wk,
    const float* __restrict__ Wv, const float* __restrict__ Wo,
    const float* __restrict__ W1, const float* __restrict__ W2,
    u16* __restrict__ wqkvb, u16* __restrict__ wob,
    u16* __restrict__ w1b, u16* __restrict__ w2b)
{
    __shared__ float tile[32][33];
    int idx = blockIdx.x;
    const int l = idx / 6912; idx -= l * 6912;
    const float* in; u16* outp; int K, N, x, y;
    if (idx < 2304) {
        int m = idx / 576, tt = idx % 576;
        x = tt % 24; y = tt / 24; K = D_; N = D_;
        const size_t wo = (size_t)l * D_ * D_;
        if (m == 0)      { in = Wq + wo; outp = wqkvb + (size_t)l * 3 * D_ * D_; }
        else if (m == 1) { in = Wk + wo; outp = wqkvb + (size_t)l * 3 * D_ * D_ + (size_t)D_ * D_; }
        else if (m == 2) { in = Wv + wo; outp = wqkvb + (size_t)l * 3 * D_ * D_ + (size_t)2 * D_ * D_; }
        else             { in = Wo + wo; outp = wob + wo; }
    } else if (idx < 4608) {
        int tt = idx - 2304;
        x = tt % 96; y = tt / 96; K = D_; N = FF_;
        in = W1 + (size_t)l * D_ * FF_; outp = w1b + (size_t)l * FF_ * D_;
    } else {
        int tt = idx - 4608;
        x = tt % 24; y = tt / 24; K = FF_; N = D_;
        in = W2 + (size_t)l * FF_ * D_; outp = w2b + (size_t)l * D_ * FF_;
    }
    const int n0 = x * 32, k0 = y * 32;
    const int tx = threadIdx.x & 31, ty = threadIdx.x >> 5;
#pragma unroll
    for (int p = 0; p < 4; p++)
        tile[ty + p * 8][tx] = in[(size_t)(k0 + ty + p * 8) * N + n0 + tx];
    __syncthreads();
#pragma unroll
    for (int p = 0; p < 4; p++)
        outp[(size_t)(n0 + ty + p * 8) * K + k0 + tx] = f2bf(tile[tx][ty + p * 8]);
}

__global__ __launch_bounds__(256) void bias_cat_kernel(
    const float* __restrict__ bq, const float* __restrict__ bk,
    const float* __restrict__ bv, float* __restrict__ o)
{
    int i = blockIdx.x * 256 + threadIdx.x;        // L_*3*D_ total
    int l = i / (3 * D_), c = i % (3 * D_);
    float v = (c < D_) ? bq[(size_t)l * D_ + c]
            : (c < 2 * D_) ? bk[(size_t)l * D_ + (c - D_)]
            : bv[(size_t)l * D_ + (c - 2 * D_)];
    o[i] = v;
}

// ---------------------------------------------------------------- embed+LN

__global__ __launch_bounds__(256) void embed_ln_kernel(
    const int* __restrict__ ids, const float* __restrict__ etok,
    const float* __restrict__ epos, const float* __restrict__ g,
    const float* __restrict__ bb, float* __restrict__ x, u16* __restrict__ xb)
{
    __shared__ float red[4];
    const int tok = blockIdx.x;
    const int s   = tok & (S_ - 1);
    const int id  = ids[tok];
    const int t   = threadIdx.x;
    float v[3];
    float sum = 0.f;
#pragma unroll
    for (int i = 0; i < 3; i++) {
        int d = t + i * 256;
        v[i] = etok[(size_t)id * D_ + d] + epos[(size_t)s * D_ + d];
        sum += v[i];
    }
    float mean = block_reduce_sum(sum, red) * (1.f / 768.f);
    float sq = 0.f;
#pragma unroll
    for (int i = 0; i < 3; i++) { float dd = v[i] - mean; sq += dd * dd; }
    float var = block_reduce_sum(sq, red) * (1.f / 768.f);
    float inv = rsqrtf(var + 1e-12f);
#pragma unroll
    for (int i = 0; i < 3; i++) {
        int d = t + i * 256;
        float o = (v[i] - mean) * inv * g[d] + bb[d];
        x[(size_t)tok * D_ + d] = o;
        xb[(size_t)tok * D_ + d] = f2bf(o);
    }
}

// ---------------------------------------------------------------- add + LN (in-place on x; also writes bf16 xb)

template <int YB>
__global__ __launch_bounds__(256) void add_ln_kernel(
    float* __restrict__ x, const float* __restrict__ y,
    const float* __restrict__ yb,
    const float* __restrict__ g, const float* __restrict__ bb,
    u16* __restrict__ xb)
{
    __shared__ float red[4];
    const int tok = blockIdx.x;
    const int t   = threadIdx.x;
    float* xr = x + (size_t)tok * D_;
    const float* yr = y + (size_t)tok * D_;
    float v[3];
    float sum = 0.f;
#pragma unroll
    for (int i = 0; i < 3; i++) {
        int d = t + i * 256;
        float bv = 0.f;
        if constexpr (YB) bv = yb[d];
        v[i] = xr[d] + yr[d] + bv;
        sum += v[i];
    }
    float mean = block_reduce_sum(sum, red) * (1.f / 768.f);
    float sq = 0.f;
#pragma unroll
    for (int i = 0; i < 3; i++) { float dd = v[i] - mean; sq += dd * dd; }
    float var = block_reduce_sum(sq, red) * (1.f / 768.f);
    float inv = rsqrtf(var + 1e-12f);
#pragma unroll
    for (int i = 0; i < 3; i++) {
        int d = t + i * 256;
        float o = (v[i] - mean) * inv * g[d] + bb[d];
        xr[d] = o;
        xb[(size_t)tok * D_ + d] = f2bf(o);
    }
}

// ---------------------------------------------------------------- bf16 MFMA GEMM (128x128 tile, 256 thr)
// Double-buffered LDS, ONE barrier per K-step; GLDS swizzle; XCD swizzle.
// Used for the small-N GEMMs (ff2, ctxWo: N=768 -> 384 blocks, 1.5/CU).

template <int ACT, int OBF, int NN, int KK>
__global__ __launch_bounds__(256) void gemm_bf16_kernel(
    const u16* __restrict__ A, const u16* __restrict__ Wt,
    const float* __restrict__ bias, void* __restrict__ Cv)
{
    __shared__ __align__(16) u16 As[2][4096];   // 128x32 bf16 x2
    __shared__ __align__(16) u16 Bs[2][4096];
    const int t = threadIdx.x;
    const int gx = gridDim.x;
    const int lid = xcd_lid();
    const int row0 = (lid / gx) * 128, col0 = (lid % gx) * 128;
    const int w = t >> 6, lane = t & 63;
    const int wr = w >> 1, wc = w & 1;
    const int i16 = lane & 15, qd = lane >> 4;

    const f32x4 zero = {0.f, 0.f, 0.f, 0.f};
    f32x4 acc[4][4];
#pragma unroll
    for (int r = 0; r < 4; r++)
#pragma unroll
        for (int c = 0; c < 4; c++) acc[r][c] = zero;

    const int e0 = t, e1 = t + 256;
    const int ra0 = e0 >> 2, ca0 = e0 & 3;
    const int ra1 = e1 >> 2, ca1 = e1 & 3;
    const int lds0 = GLDS(ra0 >> 4, ca0, ra0 & 15);
    const int lds1 = GLDS(ra1 >> 4, ca1, ra1 & 15);

    uint4 a0, a1, b0, b1;
    a0 = *(const uint4*)(A + (size_t)(row0 + ra0) * KK + ca0 * 8);
    a1 = *(const uint4*)(A + (size_t)(row0 + ra1) * KK + ca1 * 8);
    b0 = *(const uint4*)(Wt + (size_t)(col0 + ra0) * KK + ca0 * 8);
    b1 = *(const uint4*)(Wt + (size_t)(col0 + ra1) * KK + ca1 * 8);
    *(uint4*)&As[0][lds0] = a0;
    *(uint4*)&As[0][lds1] = a1;
    *(uint4*)&Bs[0][lds0] = b0;
    *(uint4*)&Bs[0][lds1] = b1;
    __syncthreads();

#pragma unroll 2
    for (int k0 = 0; k0 < KK; k0 += 32) {
        const int buf = (k0 >> 5) & 1;
        const bool more = (k0 + 32 < KK);
        if (more) {                        // issue next-tile loads early
            int kn = k0 + 32;
            a0 = *(const uint4*)(A + (size_t)(row0 + ra0) * KK + kn + ca0 * 8);
            a1 = *(const uint4*)(A + (size_t)(row0 + ra1) * KK + kn + ca1 * 8);
            b0 = *(const uint4*)(Wt + (size_t)(col0 + ra0) * KK + kn + ca0 * 8);
            b1 = *(const uint4*)(Wt + (size_t)(col0 + ra1) * KK + kn + ca1 * 8);
        }
        bf16x8 af[4], bfr[4];
#pragma unroll
        for (int r = 0; r < 4; r++)
            af[r] = *(const bf16x8*)&As[buf][GLDS(wr * 4 + r, qd, i16)];
#pragma unroll
        for (int c = 0; c < 4; c++)
            bfr[c] = *(const bf16x8*)&Bs[buf][GLDS(wc * 4 + c, qd, i16)];
#pragma unroll
        for (int r = 0; r < 4; r++)
#pragma unroll
            for (int c = 0; c < 4; c++)
                acc[r][c] = __builtin_amdgcn_mfma_f32_16x16x32_bf16(af[r], bfr[c], acc[r][c], 0, 0, 0);
        if (more) {                        // write next tile into other buffer
            *(uint4*)&As[buf ^ 1][lds0] = a0;
            *(uint4*)&As[buf ^ 1][lds1] = a1;
            *(uint4*)&Bs[buf ^ 1][lds0] = b0;
            *(uint4*)&Bs[buf ^ 1][lds1] = b1;
            __syncthreads();
        }
    }

#pragma unroll
    for (int c = 0; c < 4; c++) {
        int colg = col0 + wc * 64 + c * 16 + i16;
        float bsv = bias[colg];
#pragma unroll
        for (int r = 0; r < 4; r++) {
            int rowb = row0 + wr * 64 + r * 16 + qd * 4;
#pragma unroll
            for (int p = 0; p < 4; p++) {
                float val = acc[r][c][p] + bsv;
                if (ACT == 1) val = gelu_f(val);
                if (OBF == 1)
                    ((u16*)Cv)[(size_t)(rowb + p) * NN + colg] = f2bf(val);
                else
                    ((float*)Cv)[(size_t)(rowb + p) * NN + colg] = val;
            }
        }
    }
}

// ---------------------------------------------------------------- bf16 MFMA GEMM (256x128 tile, 512 thr)
// r14: same verified 2-phase sync structure, DOUBLED row-tile: 8 waves
// (4 row x 2 col), per-wave code identical to the 128^2 kernel (64x64 acc).
// Halves barrier-drains per output and B-panel HBM fetches; per-thread
// staging drops 4->3 uint4. LDS 48KB -> 3 blocks/CU (24 waves/CU, unchanged).

template <int ACT, int OBF, int NN, int KK>
__global__ __launch_bounds__(512) void gemm_bf16_256_kernel(
    const u16* __restrict__ A, const u16* __restrict__ Wt,
    const float* __restrict__ bias, void* __restrict__ Cv)
{
    __shared__ __align__(16) u16 As[2][8192];   // 256x32 bf16 x2
    __shared__ __align__(16) u16 Bs[2][4096];   // 128x32 bf16 x2
    const int t = threadIdx.x;
    const int gx = gridDim.x;
    const int lid = xcd_lid();
    const int row0 = (lid / gx) * 256, col0 = (lid % gx) * 128;
    const int w = t >> 6, lane = t & 63;
    const int wr = w >> 1, wc = w & 1;      // wr 0..3 (64-row bands), wc 0..1
    const int i16 = lane & 15, qd = lane >> 4;

    const f32x4 zero = {0.f, 0.f, 0.f, 0.f};
    f32x4 acc[4][4];
#pragma unroll
    for (int r = 0; r < 4; r++)
#pragma unroll
        for (int c = 0; c < 4; c++) acc[r][c] = zero;

    // staging: A slots t (rows 0..127) and t+512 (rows 128..255); B slot t
    const int ra0 = t >> 2, ca = t & 3;
    const int ra1 = ra0 + 128;
    const int ldsA0 = GLDS(ra0 >> 4, ca, ra0 & 15);
    const int ldsA1 = GLDS(ra1 >> 4, ca, ra1 & 15);
    const int ldsB  = ldsA0;                 // rb = ra0 (0..127), cb = ca

    uint4 a0, a1, b0;
    a0 = *(const uint4*)(A + (size_t)(row0 + ra0) * KK + ca * 8);
    a1 = *(const uint4*)(A + (size_t)(row0 + ra1) * KK + ca * 8);
    b0 = *(const uint4*)(Wt + (size_t)(col0 + ra0) * KK + ca * 8);
    *(uint4*)&As[0][ldsA0] = a0;
    *(uint4*)&As[0][ldsA1] = a1;
    *(uint4*)&Bs[0][ldsB]  = b0;
    __syncthreads();

#pragma unroll 2
    for (int k0 = 0; k0 < KK; k0 += 32) {
        const int buf = (k0 >> 5) & 1;
        const bool more = (k0 + 32 < KK);
        if (more) {                        // issue next-tile loads early
            int kn = k0 + 32;
            a0 = *(const uint4*)(A + (size_t)(row0 + ra0) * KK + kn + ca * 8);
            a1 = *(const uint4*)(A + (size_t)(row0 + ra1) * KK + kn + ca * 8);
            b0 = *(const uint4*)(Wt + (size_t)(col0 + ra0) * KK + kn + ca * 8);
        }
        bf16x8 af[4], bfr[4];
#pragma unroll
        for (int r = 0; r < 4; r++)
            af[r] = *(const bf16x8*)&As[buf][GLDS(wr * 4 + r, qd, i16)];   // rowgrp 0..15
#pragma unroll
        for (int c = 0; c < 4; c++)
            bfr[c] = *(const bf16x8*)&Bs[buf][GLDS(wc * 4 + c, qd, i16)];  // rowgrp 0..7
#pragma unroll
        for (int r = 0; r < 4; r++)
#pragma unroll
            for (int c = 0; c < 4; c++)
                acc[r][c] = __builtin_amdgcn_mfma_f32_16x16x32_bf16(af[r], bfr[c], acc[r][c], 0, 0, 0);
        if (more) {                        // write next tile into other buffer
            *(uint4*)&As[buf ^ 1][ldsA0] = a0;
            *(uint4*)&As[buf ^ 1][ldsA1] = a1;
            *(uint4*)&Bs[buf ^ 1][ldsB]  = b0;
            __syncthreads();
        }
    }

#pragma unroll
    for (int c = 0; c < 4; c++) {
        int colg = col0 + wc * 64 + c * 16 + i16;
        float bsv = bias[colg];
#pragma unroll
        for (int r = 0; r < 4; r++) {
            int rowb = row0 + wr * 64 + r * 16 + qd * 4;
#pragma unroll
            for (int p = 0; p < 4; p++) {
                float val = acc[r][c][p] + bsv;
                if (ACT == 1) val = gelu_f(val);
                if (OBF == 1)
                    ((u16*)Cv)[(size_t)(rowb + p) * NN + colg] = f2bf(val);
                else
                    ((float*)Cv)[(size_t)(rowb + p) * NN + colg] = val;
            }
        }
    }
}

// ---------------------------------------------------------------- fused QKV GEMM (256x128 tile, 512 thr; NN=2304, KK=768)
// Q,K -> fused [M,1536] bf16; V -> transposed global [B][H][DH][S] bf16
// r14: same 256-row geometry as gemm_bf16_256_kernel.

__global__ __launch_bounds__(512) void gemm_qkv_kernel(
    const u16* __restrict__ A, const u16* __restrict__ Wt,
    const float* __restrict__ bias, u16* __restrict__ qk, u16* __restrict__ vtg)
{
    __shared__ __align__(16) u16 As[2][8192];
    __shared__ __align__(16) u16 Bs[2][4096];
    const int t = threadIdx.x;
    const int gx = gridDim.x;
    const int lid = xcd_lid();
    const int row0 = (lid / gx) * 256, col0 = (lid % gx) * 128;
    const int w = t >> 6, lane = t & 63;
    const int wr = w >> 1, wc = w & 1;
    const int i16 = lane & 15, qd = lane >> 4;

    const f32x4 zero = {0.f, 0.f, 0.f, 0.f};
    f32x4 acc[4][4];
#pragma unroll
    for (int r = 0; r < 4; r++)
#pragma unroll
        for (int c = 0; c < 4; c++) acc[r][c] = zero;

    const int ra0 = t >> 2, ca = t & 3;
    const int ra1 = ra0 + 128;
    const int ldsA0 = GLDS(ra0 >> 4, ca, ra0 & 15);
    const int ldsA1 = GLDS(ra1 >> 4, ca, ra1 & 15);
    const int ldsB  = ldsA0;

    uint4 a0, a1, b0;
    a0 = *(const uint4*)(A + (size_t)(row0 + ra0) * D_ + ca * 8);
    a1 = *(const uint4*)(A + (size_t)(row0 + ra1) * D_ + ca * 8);
    b0 = *(const uint4*)(Wt + (size_t)(col0 + ra0) * D_ + ca * 8);
    *(uint4*)&As[0][ldsA0] = a0;
    *(uint4*)&As[0][ldsA1] = a1;
    *(uint4*)&Bs[0][ldsB]  = b0;
    __syncthreads();

#pragma unroll 2
    for (int k0 = 0; k0 < D_; k0 += 32) {
        const int buf = (k0 >> 5) & 1;
        const bool more = (k0 + 32 < D_);
        if (more) {
            int kn = k0 + 32;
            a0 = *(const uint4*)(A + (size_t)(row0 + ra0) * D_ + kn + ca * 8);
            a1 = *(const uint4*)(A + (size_t)(row0 + ra1) * D_ + kn + ca * 8);
            b0 = *(const uint4*)(Wt + (size_t)(col0 + ra0) * D_ + kn + ca * 8);
        }
        bf16x8 af[4], bfr[4];
#pragma unroll
        for (int r = 0; r < 4; r++)
            af[r] = *(const bf16x8*)&As[buf][GLDS(wr * 4 + r, qd, i16)];
#pragma unroll
        for (int c = 0; c < 4; c++)
            bfr[c] = *(const bf16x8*)&Bs[buf][GLDS(wc * 4 + c, qd, i16)];
#pragma unroll
        for (int r = 0; r < 4; r++)
#pragma unroll
            for (int c = 0; c < 4; c++)
                acc[r][c] = __builtin_amdgcn_mfma_f32_16x16x32_bf16(af[r], bfr[c], acc[r][c], 0, 0, 0);
        if (more) {
            *(uint4*)&As[buf ^ 1][ldsA0] = a0;
            *(uint4*)&As[buf ^ 1][ldsA1] = a1;
            *(uint4*)&Bs[buf ^ 1][ldsB]  = b0;
            __syncthreads();
        }
    }

#pragma unroll
    for (int c = 0; c < 4; c++) {
        int colg = col0 + wc * 64 + c * 16 + i16;
        float bsv = bias[colg];
        if (colg < QK2S_) {                          // Q|K region
#pragma unroll
            for (int r = 0; r < 4; r++) {
                int rowb = row0 + wr * 64 + r * 16 + qd * 4;
#pragma unroll
                for (int p = 0; p < 4; p++)
                    qk[(size_t)(rowb + p) * QK2S_ + colg] = f2bf(acc[r][c][p] + bsv);
            }
        } else {                                     // V region -> transposed [B][H][DH][S]
            int cv = colg - QK2S_;
            int h = cv >> 6, d = cv & 63;
#pragma unroll
            for (int r = 0; r < 4; r++) {
                int rowb = row0 + wr * 64 + r * 16 + qd * 4;
                int bb = rowb >> 12, ss = rowb & (S_ - 1);
                uint2 o;
                o.x = (unsigned)f2bf(acc[r][c][0] + bsv) | ((unsigned)f2bf(acc[r][c][1] + bsv) << 16);
                o.y = (unsigned)f2bf(acc[r][c][2] + bsv) | ((unsigned)f2bf(acc[r][c][3] + bsv) << 16);
                *(uint2*)(vtg + (((size_t)(bb * H_ + h) * DH_ + d) * S_ + ss)) = o;
            }
        }
    }
}

// ---------------------------------------------------------------- MFMA attention core (coalesced cooperative staging)
// Each 64B line of K/V/Q fetched from global EXACTLY ONCE per block (8
// consecutive lanes cover one 128B row-segment), staged into XOR-swizzled LDS;
// all 4 waves read MFMA fragments from LDS. Double-buffered K/V, ONE barrier
// per key-block; loads issue at iteration top, ds_write after compute.
// P = exp(s/8 - SOFT_SHIFT); Ps is wave-private (in-order DS -> no barrier).
// O and l are unnormalized-but-consistent; caller divides.

__device__ inline void attn_core(
    const u16* __restrict__ qtile,   // qk + (b*S + qb*64)*1536 + h*64
    const u16* __restrict__ kbh,     // qk + 768 + b*S*1536 + h*64
    const u16* __restrict__ vth,     // vtg + (b*H + h)*64*S
    const int* kbl,                  // 8 key-block indices
    u16* Qs, u16* Ks, u16* Vs, u16* Ps,
    f32x4 (&o)[4], float (&l)[4])
{
    const int t = threadIdx.x;
    const int w = t >> 6, lane = t & 63;
    const int l15 = lane & 15, quad = lane >> 4;

    // staging mapping: thread covers 16B chunk c8w of rows r0 (li=0) / r1 (li=1)
    const int rsub = lane >> 3;            // 0..7
    const int c8w  = lane & 7;             // 0..7
    const int r0s  = w * 8 + rsub;         // rows 0..31 across waves
    const int r1s  = r0s + 32;             // rows 32..63
    const int soff0 = (r0s * 8 + (c8w ^ (r0s & 7))) * 8;   // u16 index
    const int soff1 = (r1s * 8 + (c8w ^ (r1s & 7))) * 8;

    // ---- prologue: stage Q + first K/V block (each line fetched once)
    {
        uint4 q0 = *(const uint4*)(qtile + (size_t)r0s * QK2S_ + c8w * 8);
        uint4 q1 = *(const uint4*)(qtile + (size_t)r1s * QK2S_ + c8w * 8);
        const u16* kb0 = kbh + (size_t)kbl[0] * BLK_ * QK2S_;
        const u16* vb0 = vth + kbl[0] * BLK_;
        uint4 k0 = *(const uint4*)(kb0 + (size_t)r0s * QK2S_ + c8w * 8);
        uint4 k1 = *(const uint4*)(kb0 + (size_t)r1s * QK2S_ + c8w * 8);
        uint4 v0 = *(const uint4*)(vb0 + (size_t)r0s * S_ + c8w * 8);
        uint4 v1 = *(const uint4*)(vb0 + (size_t)r1s * S_ + c8w * 8);
        *(uint4*)&Qs[soff0] = q0;  *(uint4*)&Qs[soff1] = q1;
        *(uint4*)&Ks[soff0] = k0;  *(uint4*)&Ks[soff1] = k1;
        *(uint4*)&Vs[soff0] = v0;  *(uint4*)&Vs[soff1] = v1;
    }
    __syncthreads();

    // Q fragments: row w*16+l15, chunk ki*4+quad (swizzled) -> regs, once
    const int xq = l15 & 7;
    bf16x8 qf[2];
#pragma unroll
    for (int ki = 0; ki < 2; ki++)
        qf[ki] = *(const bf16x8*)&Qs[((w * 16 + l15) * 8 + ((ki * 4 + quad) ^ xq)) * 8];

    const f32x4 zero = {0.f, 0.f, 0.f, 0.f};
#pragma unroll
    for (int c = 0; c < 4; c++) o[c] = zero;
    float ps[4] = {0.f, 0.f, 0.f, 0.f};

    const int wxor = (quad >> 1) << 4;            // P write rows quad*4+r: row bit3 = quad>>1
    const int rxor = ((l15 >> 3) & 1) << 4;       // P read row l15: row bit3 = l15>>3
    u16* pw = Ps + (w * 16 + quad * 4) * PSTR;
    const u16* pr = Ps + (w * 16 + l15) * PSTR;

    uint4 k0n, k1n, v0n, v1n;
#pragma unroll
    for (int kbi = 0; kbi < 8; kbi++) {
        // issue next block's staging loads early (hidden under this iteration)
        if (kbi + 1 < 8) {
            const u16* kbn = kbh + (size_t)kbl[kbi + 1] * BLK_ * QK2S_;
            const u16* vbn = vth + kbl[kbi + 1] * BLK_;
            k0n = *(const uint4*)(kbn + (size_t)r0s * QK2S_ + c8w * 8);
            k1n = *(const uint4*)(kbn + (size_t)r1s * QK2S_ + c8w * 8);
            v0n = *(const uint4*)(vbn + (size_t)r0s * S_ + c8w * 8);
            v1n = *(const uint4*)(vbn + (size_t)r1s * S_ + c8w * 8);
        }
        const u16* Kc = Ks + (kbi & 1) * 4096;
        const u16* Vc = Vs + (kbi & 1) * 4096;
        bf16x8 kf[4][2], vf[4][2];
#pragma unroll
        for (int c = 0; c < 4; c++)
#pragma unroll
            for (int ki = 0; ki < 2; ki++) {
                const int off = ((c * 16 + l15) * 8 + ((ki * 4 + quad) ^ xq)) * 8;
                kf[c][ki] = *(const bf16x8*)&Kc[off];
                vf[c][ki] = *(const bf16x8*)&Vc[off];
            }
        f32x4 s[4];
#pragma unroll
        for (int c = 0; c < 4; c++) s[c] = zero;
#pragma unroll
        for (int ki = 0; ki < 2; ki++)
#pragma unroll
            for (int c = 0; c < 4; c++)
                s[c] = __builtin_amdgcn_mfma_f32_16x16x32_bf16(qf[ki], kf[c][ki], s[c], 0, 0, 0);
        // constant-shift softmax numerator, in place in s
#pragma unroll
        for (int c = 0; c < 4; c++)
#pragma unroll
            for (int r = 0; r < 4; r++)
                s[c][r] = __expf(fmaf(s[c][r], 0.125f, -SOFT_SHIFT));
#pragma unroll
        for (int r = 0; r < 4; r++)
            ps[r] += (s[0][r] + s[1][r]) + (s[2][r] + s[3][r]);
        // P -> wave-private LDS (swizzled, static indexing, no barrier)
#pragma unroll
        for (int c = 0; c < 4; c++) {
            const int cbase = (c * 16 + l15) ^ wxor;
#pragma unroll
            for (int r = 0; r < 4; r++)
                pw[r * PSTR + cbase] = f2bf(s[c][r]);
        }
        // P fragments + PV (DS ops in-order per wave: reads see the writes)
#pragma unroll
        for (int ki = 0; ki < 2; ki++) {
            bf16x8 pf = *(const bf16x8*)(pr + ((ki * 32 + quad * 8) ^ rxor));
#pragma unroll
            for (int c = 0; c < 4; c++)
                o[c] = __builtin_amdgcn_mfma_f32_16x16x32_bf16(pf, vf[c][ki], o[c], 0, 0, 0);
        }
        // write next block into the other buffer; one barrier per iteration
        if (kbi + 1 < 8) {
            u16* Kn = Ks + ((kbi + 1) & 1) * 4096;
            u16* Vn = Vs + ((kbi + 1) & 1) * 4096;
            *(uint4*)&Kn[soff0] = k0n;  *(uint4*)&Kn[soff1] = k1n;
            *(uint4*)&Vn[soff0] = v0n;  *(uint4*)&Vn[soff1] = v1n;
            __syncthreads();
        }
    }
    // single final row-sum reduce across the 16 key lanes
#pragma unroll
    for (int r = 0; r < 4; r++) {
        float v = ps[r];
        v += __shfl_xor(v, 1, 16);
        v += __shfl_xor(v, 2, 16);
        v += __shfl_xor(v, 4, 16);
        v += __shfl_xor(v, 8, 16);
        l[r] = v;
    }
}

// ---------------------------------------------------------------- merged attention (sparse qblocks 1..62 + full-row chunks)

__global__ __launch_bounds__(256) void attn_kernel(
    const u16* __restrict__ qk, const u16* __restrict__ vtg,
    const int* __restrict__ rnd, u16* __restrict__ ctx,
    float* __restrict__ pctx, float* __restrict__ pl)
{
    __shared__ __align__(16) u16 Qs[4096];
    __shared__ __align__(16) u16 Ks[2 * 4096];
    __shared__ __align__(16) u16 Vs[2 * 4096];
    __shared__ __align__(16) u16 Ps[BLK_ * PSTR];

    // XCD-aware bijective swizzle: 1872 blocks = 8 XCDs x 234. Consecutive
    // logical ids (same (b,h), adjacent qblocks -> shared K/V) land on one XCD.
    const int hid = blockIdx.x + 78 * (blockIdx.y + H_ * blockIdx.z);
    const int lid = (hid & 7) * 234 + (hid >> 3);
    const int xk = lid % 78;
    const int yz = lid / 78;
    const int h = yz % H_;
    const int b = yz / H_;

    const int t = threadIdx.x;
    const int w = t >> 6, lane = t & 63;
    const int l15 = lane & 15, quad = lane >> 4;

    const bool sparse = (xk < 62);
    int qb, kbl[8], ci = 0;
    if (sparse) {
        qb = xk + 1;
        const int* rp = rnd + ((size_t)(h * NB_ + qb)) * R_;
        kbl[0] = 0; kbl[1] = qb - 1; kbl[2] = qb; kbl[3] = qb + 1;
        kbl[4] = NB_ - 1; kbl[5] = rp[0]; kbl[6] = rp[1]; kbl[7] = rp[2];
    } else {
        int e = xk - 62;
        int chunk = e & 7, qsel = e >> 3;
        qb = qsel ? (NB_ - 1) : 0;
#pragma unroll
        for (int i = 0; i < 8; i++) kbl[i] = chunk * 8 + i;
        ci = (((qsel * B_ + b) * H_ + h) * NCH_) + chunk;
    }

    const u16* qtile = qk + ((size_t)(b * S_ + qb * BLK_)) * QK2S_ + h * DH_;
    const u16* kbh   = qk + D_ + ((size_t)b * S_) * QK2S_ + h * DH_;
    const u16* vth   = vtg + ((size_t)(b * H_ + h) * DH_) * S_;

    f32x4 o[4]; float l[4];
    attn_core(qtile, kbh, vth, kbl, Qs, Ks, Vs, Ps, o, l);

    if (sparse) {
#pragma unroll
        for (int r = 0; r < 4; r++) {
            int row = w * 16 + quad * 4 + r;
            float inv = 1.f / l[r];
#pragma unroll
            for (int c = 0; c < 4; c++)
                ctx[((size_t)(b * S_ + qb * BLK_ + row)) * D_ + h * DH_ + c * 16 + l15] =
                    f2bf(o[c][r] * inv);
        }
    } else {
#pragma unroll
        for (int r = 0; r < 4; r++) {
            int row = w * 16 + quad * 4 + r;
#pragma unroll
            for (int c = 0; c < 4; c++)
                pctx[((size_t)ci * BLK_ + row) * DH_ + c * 16 + l15] = o[c][r];
            if (l15 == 0)
                pl[(size_t)ci * BLK_ + row] = l[r];
        }
    }
}

// combine: with constant shift, partials add directly (no max re-alignment)
__global__ __launch_bounds__(256) void attn_combine_kernel(
    const float* __restrict__ pctx, const float* __restrict__ pl,
    u16* __restrict__ ctx)
{
    const int qsel = blockIdx.x, h = blockIdx.y, b = blockIdx.z;
    const int qb = qsel ? (NB_ - 1) : 0;
    const int t = threadIdx.x;
    const int row = t >> 2, q4 = t & 3;
    const int cbase = ((qsel * B_ + b) * H_ + h) * NCH_;

    float L = 0.f;
#pragma unroll
    for (int c = 0; c < NCH_; c++) L += pl[(size_t)(cbase + c) * BLK_ + row];

    float acc[16];
#pragma unroll
    for (int j = 0; j < 16; j++) acc[j] = 0.f;
#pragma unroll
    for (int c = 0; c < NCH_; c++) {
        const float* src = pctx + ((size_t)(cbase + c) * BLK_ + row) * DH_ + q4 * 16;
#pragma unroll
        for (int jj = 0; jj < 4; jj++) {
            float4 f = *(const float4*)(src + jj * 4);
            acc[jj * 4 + 0] += f.x;
            acc[jj * 4 + 1] += f.y;
            acc[jj * 4 + 2] += f.z;
            acc[jj * 4 + 3] += f.w;
        }
    }
    float invL = 1.f / L;
    u16* dst = ctx + ((size_t)(b * S_ + qb * BLK_ + row)) * D_ + h * DH_ + q4 * 16;
    uint4 o0, o1;
#pragma unroll
    for (int g = 0; g < 8; g++) {
        unsigned lo = (unsigned)f2bf(acc[g * 2 + 0] * invL);
        unsigned hi = (unsigned)f2bf(acc[g * 2 + 1] * invL);
        unsigned pk = lo | (hi << 16);
        if (g < 4) (&o0.x)[g] = pk; else (&o1.x)[g - 4] = pk;
    }
    *(uint4*)dst = o0;
    *(uint4*)(dst + 8) = o1;
}

// ---------------------------------------------------------------- pooling + final dot

__global__ __launch_bounds__(256) void pool_kernel(
    const float* __restrict__ x, const float* __restrict__ fcw,
    float* __restrict__ acc)
{
    __shared__ float red[4];
    const int chunk = blockIdx.x, b = blockIdx.y;
    const int t = threadIdx.x;
    float s = 0.f;
    for (int sr = 0; sr < 128; sr++) {
        const float* xr = x + ((size_t)(b * S_ + chunk * 128 + sr)) * D_;
#pragma unroll
        for (int i = 0; i < 3; i++) {
            int d = t + i * 256;
            s += xr[d] * fcw[d];
        }
    }
    float tot = block_reduce_sum(s, red);
    if (t == 0) atomicAdd(&acc[b], tot);
}

__global__ void final_kernel(const float* __restrict__ acc,
                             const float* __restrict__ fcb,
                             float* __restrict__ out)
{
    if (threadIdx.x < B_) out[threadIdx.x] = acc[threadIdx.x] * (1.f / S_) + fcb[0];
}

// ---------------------------------------------------------------- launch

extern "C" void kernel_launch(void* const* d_in, const int* in_sizes, int n_in,
                              void* d_out, int out_size, void* d_ws, size_t ws_size,
                              hipStream_t stream)
{
    (void)in_sizes; (void)n_in; (void)out_size; (void)ws_size;
    const int*   ids  = (const int*)d_in[0];
    const int*   rnd  = (const int*)d_in[1];
    const float* etok = (const float*)d_in[2];
    const float* epos = (const float*)d_in[3];
    const float* lng  = (const float*)d_in[4];
    const float* lnb  = (const float*)d_in[5];
    const float* Wq   = (const float*)d_in[6];
    const float* bq   = (const float*)d_in[7];
    const float* Wk   = (const float*)d_in[8];
    const float* bk   = (const float*)d_in[9];
    const float* Wv   = (const float*)d_in[10];
    const float* bv   = (const float*)d_in[11];
    const float* Wo   = (const float*)d_in[12];
    const float* bo   = (const float*)d_in[13];
    const float* ln1g = (const float*)d_in[14];
    const float* ln1b = (const float*)d_in[15];
    const float* W1   = (const float*)d_in[16];
    const float* b1   = (const float*)d_in[17];
    const float* W2   = (const float*)d_in[18];
    const float* b2   = (const float*)d_in[19];
    const float* ln2g = (const float*)d_in[20];
    const float* ln2b = (const float*)d_in[21];
    const float* fcw  = (const float*)d_in[22];
    const float* fcb  = (const float*)d_in[23];
    float* out = (float*)d_out;

    // ---- workspace layout (~148 MB) ----
    const size_t MD = (size_t)M_ * D_;
    const size_t PCTX = (size_t)2 * B_ * H_ * NCH_ * BLK_ * DH_;
    const size_t PML  = (size_t)2 * B_ * H_ * NCH_ * BLK_;

    float* x     = (float*)d_ws;              // MD f32
    float* regB  = x + MD;                    // MD f32
    float* pctx  = regB + MD;                 // PCTX f32
    float* pl    = pctx + PCTX;               // PML f32
    u16*   qkb   = (u16*)(pl + PML);          // 2*MD bf16 (fused q|k per row)
    u16*   vtg   = qkb + 2 * MD;              // MD bf16, [B][H][DH][S]
    u16*   ctxb  = vtg + MD;                  // MD bf16
    u16*   ffhb  = qkb;                       // [M,FF] bf16, aliases qkb+vtg+ctxb
    u16*   xb    = ctxb + MD;                 // MD bf16
    u16*   wqkvb = xb + MD;                   // L*2304*768 bf16
    u16*   wob   = wqkvb + (size_t)L_ * 3 * D_ * D_;
    u16*   w1b   = wob + (size_t)L_ * D_ * D_;       // [L][FF][D]
    u16*   w2b   = w1b + (size_t)L_ * FF_ * D_;      // [L][D][FF]
    float* bqkv  = (float*)(w2b + (size_t)L_ * D_ * FF_);  // L*2304 f32
    float* acc   = bqkv + (size_t)L_ * 3 * D_;

    hipMemsetAsync(acc, 0, 2 * sizeof(float), stream);

    tcast_all_kernel<<<L_ * 6912, 256, 0, stream>>>(
        Wq, Wk, Wv, Wo, W1, W2, wqkvb, wob, w1b, w2b);
    bias_cat_kernel<<<(L_ * 3 * D_) / 256, 256, 0, stream>>>(bq, bk, bv, bqkv);
    embed_ln_kernel<<<M_, 256, 0, stream>>>(ids, etok, epos, lng, lnb, x, xb);

    dim3 gQKV(3 * D_ / 128, M_ / 256);     // (18, 32) = 576 blocks (%8==0)
    dim3 g6(D_ / 128, M_ / 128);           // (6, 64)  = 384 blocks (%8==0)
    dim3 gF(FF_ / 128, M_ / 256);          // (24, 32) = 768 blocks (%8==0)
    for (int l = 0; l < L_; l++) {
        const size_t wo = (size_t)l * D_ * D_;
        const size_t vo = (size_t)l * D_;
        gemm_qkv_kernel<<<gQKV, 512, 0, stream>>>(
            xb, wqkvb + (size_t)l * 3 * D_ * D_, bqkv + (size_t)l * 3 * D_, qkb, vtg);
        attn_kernel<<<dim3(78, H_, B_), 256, 0, stream>>>(qkb, vtg, rnd, ctxb, pctx, pl);
        attn_combine_kernel<<<dim3(2, H_, B_), 256, 0, stream>>>(pctx, pl, ctxb);
        gemm_bf16_kernel<0, 0, D_, D_><<<g6, 256, 0, stream>>>(
            ctxb, wob + wo, bo + vo, regB);
        add_ln_kernel<0><<<M_, 256, 0, stream>>>(x, regB, nullptr, ln1g + vo, ln1b + vo, xb);
        gemm_bf16_256_kernel<1, 1, FF_, D_><<<gF, 512, 0, stream>>>(
            xb, w1b + (size_t)l * FF_ * D_, b1 + (size_t)l * FF_, ffhb);
        gemm_bf16_kernel<0, 0, D_, FF_><<<g6, 256, 0, stream>>>(
            ffhb, w2b + (size_t)l * D_ * FF_, b2 + vo, regB);
        add_ln_kernel<0><<<M_, 256, 0, stream>>>(x, regB, nullptr, ln2g + vo, ln2b + vo, xb);
    }
    pool_kernel<<<dim3(S_ / 128, B_), 256, 0, stream>>>(x, fcw, acc);
    final_kernel<<<1, 64, 0, stream>>>(acc, fcb, out);
}